// Round 1
// baseline (1077.570 us; speedup 1.0000x reference)
//
#include <hip/hip_runtime.h>
#include <cmath>

#define NSLOPE 0.2f
#define BN_EPS 1e-5f

static __device__ __forceinline__ float lrelu(float v) { return v > 0.f ? v : NSLOPE * v; }

// ---------------------------------------------------------------- init
__global__ void k_init(int* __restrict__ cursor, int* __restrict__ gstart,
                       float* __restrict__ bnstat, int N) {
  int i = blockIdx.x * blockDim.x + threadIdx.x;
  int stride = gridDim.x * blockDim.x;
  for (int j = i; j < N; j += stride) cursor[j] = 1;  // self-loop count
  if (i < 65) gstart[i] = N;
  if (i < 768) bnstat[i] = 0.f;
}

// count in-degree (into cursor) + graph starts via atomicMin
__global__ void k_count(const int* __restrict__ edst, int E,
                        int* __restrict__ cursor,
                        const int* __restrict__ batch, int N,
                        int* __restrict__ gstart) {
  int i = blockIdx.x * blockDim.x + threadIdx.x;
  int stride = gridDim.x * blockDim.x;
  int total = E > N ? E : N;
  for (int j = i; j < total; j += stride) {
    if (j < E) atomicAdd(&cursor[edst[j]], 1);
    if (j < N) atomicMin(&gstart[batch[j]], j);
  }
}

// ---------------------------------------------------------------- scan (3-phase)
__global__ __launch_bounds__(512) void k_scanA(const int* __restrict__ cnt, int N,
                                               int* __restrict__ partials) {
  int t = threadIdx.x;
  int i = blockIdx.x * 512 + t;
  int v = (i < N) ? cnt[i] : 0;
#pragma unroll
  for (int off = 32; off; off >>= 1) v += __shfl_xor(v, off);
  __shared__ int red[8];
  if ((t & 63) == 0) red[t >> 6] = v;
  __syncthreads();
  if (t == 0) {
    int s = 0;
#pragma unroll
    for (int w = 0; w < 8; ++w) s += red[w];
    partials[blockIdx.x] = s;
  }
}

__global__ void k_scanB(int* __restrict__ partials, int nchunks,
                        int* __restrict__ offsets, int N, int* __restrict__ gstart) {
  if (threadIdx.x == 0 && blockIdx.x == 0) {
    int run = 0;
    for (int b = 0; b < nchunks; ++b) { int t = partials[b]; partials[b] = run; run += t; }
    offsets[N] = run;
    // fix empty-graph starts (batch sorted)
    for (int g = 63; g >= 0; --g)
      if (gstart[g] > gstart[g + 1]) gstart[g] = gstart[g + 1];
  }
}

__global__ __launch_bounds__(512) void k_scanC(int* __restrict__ cursor, int* __restrict__ offsets,
                                               const int* __restrict__ partials, int N) {
  __shared__ int s[512];
  int t = threadIdx.x;
  int i = blockIdx.x * 512 + t;
  int c = (i < N) ? cursor[i] : 0;
  s[t] = c;
  __syncthreads();
  for (int off = 1; off < 512; off <<= 1) {
    int v = (t >= off) ? s[t - off] : 0;
    __syncthreads();
    s[t] += v;
    __syncthreads();
  }
  if (i < N) {
    int excl = s[t] - c + partials[blockIdx.x];
    offsets[i] = excl;
    cursor[i] = excl;  // scatter cursor
  }
}

__global__ void k_scatter(const int* __restrict__ esrc, const int* __restrict__ edst,
                          int E, int N, int* __restrict__ cursor, int* __restrict__ srcs) {
  int i = blockIdx.x * blockDim.x + threadIdx.x;
  int stride = gridDim.x * blockDim.x;
  int total = E + N;
  for (int j = i; j < total; j += stride) {
    int s, d;
    if (j < E) { s = esrc[j]; d = edst[j]; } else { s = j - E; d = j - E; }
    int pos = atomicAdd(&cursor[d], 1);
    srcs[pos] = s;
  }
}

// ---------------------------------------------------------------- layer-1 feature GEMM (K=8) + head scores
__global__ __launch_bounds__(128) void k_h1(const float* __restrict__ x, const float* __restrict__ W,
                                            const float* __restrict__ asrc, const float* __restrict__ adst,
                                            float* __restrict__ h1, float* __restrict__ ssrc,
                                            float* __restrict__ sdst) {
  __shared__ float sx[8];
  int n = blockIdx.x, t = threadIdx.x;
  if (t < 8) sx[t] = x[n * 8 + t];
  __syncthreads();
  float acc = 0.f;
#pragma unroll
  for (int k = 0; k < 8; ++k) acc += sx[k] * W[k * 128 + t];
  h1[(size_t)n * 128 + t] = acc;
  float ps = acc * asrc[t];  // asrc flat [4][32] == [128]
  float pd = acc * adst[t];
#pragma unroll
  for (int off = 16; off; off >>= 1) {
    ps += __shfl_xor(ps, off, 32);
    pd += __shfl_xor(pd, off, 32);
  }
  if ((t & 31) == 0) {
    int h = t >> 5;
    ssrc[n * 4 + h] = ps;
    sdst[n * 4 + h] = pd;
  }
}

// ---------------------------------------------------------------- GAT aggregation (flash-style segment softmax)
template <int F>
__global__ void k_agg(const float* __restrict__ hf, const float* __restrict__ ssrc,
                      const float* __restrict__ sdst, const int* __restrict__ offsets,
                      const int* __restrict__ srcs, const float* __restrict__ bias,
                      float* __restrict__ out) {
  constexpr int C = F / 4;
  constexpr int NW = F / 64;
  constexpr int CHUNK = 1024;
  __shared__ float4 sc[CHUNK];        // per-edge scores -> exp values (4 heads)
  __shared__ float red[NW][4];
  __shared__ float mrun[4], drun[4], scA[4];

  int n = blockIdx.x, t = threadIdx.x;
  int head = t / C;
  int wid = t >> 6, lane = t & 63;
  int beg = offsets[n];
  int deg = offsets[n + 1] - beg;

  float4 sd = *(const float4*)&sdst[n * 4];
  if (t < 4) { mrun[t] = -INFINITY; drun[t] = 0.f; }
  __syncthreads();

  float acc = 0.f;
  for (int c0 = 0; c0 < deg; c0 += CHUNK) {
    int cn = min(CHUNK, deg - c0);
    // phase A: leaky-relu scores + local max
    float lm0 = -INFINITY, lm1 = -INFINITY, lm2 = -INFINITY, lm3 = -INFINITY;
    for (int e = t; e < cn; e += F) {
      int s = srcs[beg + c0 + e];
      float4 sv = *(const float4*)&ssrc[s * 4];
      float4 v;
      v.x = lrelu(sv.x + sd.x);
      v.y = lrelu(sv.y + sd.y);
      v.z = lrelu(sv.z + sd.z);
      v.w = lrelu(sv.w + sd.w);
      sc[e] = v;
      lm0 = fmaxf(lm0, v.x); lm1 = fmaxf(lm1, v.y);
      lm2 = fmaxf(lm2, v.z); lm3 = fmaxf(lm3, v.w);
    }
#pragma unroll
    for (int off = 32; off; off >>= 1) {
      lm0 = fmaxf(lm0, __shfl_xor(lm0, off));
      lm1 = fmaxf(lm1, __shfl_xor(lm1, off));
      lm2 = fmaxf(lm2, __shfl_xor(lm2, off));
      lm3 = fmaxf(lm3, __shfl_xor(lm3, off));
    }
    if (lane == 0) { red[wid][0] = lm0; red[wid][1] = lm1; red[wid][2] = lm2; red[wid][3] = lm3; }
    __syncthreads();  // B1
    if (t < 4) {
      float mm = red[0][t];
#pragma unroll
      for (int w = 1; w < NW; ++w) mm = fmaxf(mm, red[w][t]);
      float old = mrun[t];
      float mn = fmaxf(old, mm);
      scA[t] = expf(old - mn);   // 0 on first chunk (old = -inf)
      mrun[t] = mn;
    }
    __syncthreads();  // B2
    float m0 = mrun[0], m1 = mrun[1], m2 = mrun[2], m3 = mrun[3];
    // phase A2: exponentiate in place + local sums
    float ls0 = 0, ls1 = 0, ls2 = 0, ls3 = 0;
    for (int e = t; e < cn; e += F) {
      float4 v = sc[e];
      v.x = expf(v.x - m0); v.y = expf(v.y - m1);
      v.z = expf(v.z - m2); v.w = expf(v.w - m3);
      sc[e] = v;
      ls0 += v.x; ls1 += v.y; ls2 += v.z; ls3 += v.w;
    }
#pragma unroll
    for (int off = 32; off; off >>= 1) {
      ls0 += __shfl_xor(ls0, off);
      ls1 += __shfl_xor(ls1, off);
      ls2 += __shfl_xor(ls2, off);
      ls3 += __shfl_xor(ls3, off);
    }
    if (lane == 0) { red[wid][0] = ls0; red[wid][1] = ls1; red[wid][2] = ls2; red[wid][3] = ls3; }
    __syncthreads();  // B3
    if (t < 4) {
      float ss = red[0][t];
#pragma unroll
      for (int w = 1; w < NW; ++w) ss += red[w][t];
      drun[t] = drun[t] * scA[t] + ss;
    }
    acc *= scA[head];
    // phase B: weighted gather-accumulate
#pragma unroll 4
    for (int e = 0; e < cn; ++e) {
      int s = srcs[beg + c0 + e];
      float wv = ((const float*)sc)[e * 4 + head];
      acc += wv * hf[(size_t)s * F + t];
    }
    __syncthreads();  // B5: protect sc/red before next chunk
  }
  out[(size_t)n * F + t] = acc / drun[head] + bias[t];
}

// ---------------------------------------------------------------- BN stats + apply(+ELU)
template <int F>
__global__ void k_bnstats(const float* __restrict__ x, float* __restrict__ sum,
                          float* __restrict__ sq, int N) {
  int c = threadIdx.x;
  float s = 0.f, s2 = 0.f;
  for (int r = blockIdx.x; r < N; r += gridDim.x) {
    float v = x[(size_t)r * F + c];
    s += v; s2 += v * v;
  }
  atomicAdd(&sum[c], s);
  atomicAdd(&sq[c], s2);
}

template <int F>
__global__ void k_bnapply(float* __restrict__ x, const float* __restrict__ sum,
                          const float* __restrict__ sq, const float* __restrict__ gamma,
                          const float* __restrict__ beta, int N) {
  size_t total = (size_t)N * F;
  size_t stride = (size_t)gridDim.x * blockDim.x;
  for (size_t idx = (size_t)blockIdx.x * blockDim.x + threadIdx.x; idx < total; idx += stride) {
    int c = (int)(idx & (F - 1));
    float mean = sum[c] * (1.0f / N);
    float var = sq[c] * (1.0f / N) - mean * mean;
    float inv = rsqrtf(var + BN_EPS);
    float y = gamma[c] * ((x[idx] - mean) * inv) + beta[c];
    x[idx] = y > 0.f ? y : expm1f(y);
  }
}

// ---------------------------------------------------------------- GEMM2: [M,128] @ [128,256]
__global__ __launch_bounds__(256) void k_gemm2(const float* __restrict__ A,
                                               const float* __restrict__ B,
                                               float* __restrict__ Cm, int M) {
  __shared__ float Al[128][64];  // transposed A tile [k][m]
  int m0 = blockIdx.x * 64;
  int tid = threadIdx.x;
  {
    int ml = tid & 63;
    int kg = tid >> 6;  // 0..3
    int row = m0 + ml;
    const float* arow = A + (size_t)row * 128;
#pragma unroll
    for (int it = 0; it < 8; ++it) {
      int k4 = kg + 4 * it;
      float4 v = make_float4(0.f, 0.f, 0.f, 0.f);
      if (row < M) v = *(const float4*)(arow + k4 * 4);
      Al[k4 * 4 + 0][ml] = v.x;
      Al[k4 * 4 + 1][ml] = v.y;
      Al[k4 * 4 + 2][ml] = v.z;
      Al[k4 * 4 + 3][ml] = v.w;
    }
  }
  __syncthreads();
  int tx = tid & 31, ty = tid >> 5;
  float acc[8][8];
#pragma unroll
  for (int r = 0; r < 8; ++r)
#pragma unroll
    for (int c = 0; c < 8; ++c) acc[r][c] = 0.f;
  const float* bp = B + tx * 8;
#pragma unroll 4
  for (int k = 0; k < 128; ++k) {
    float4 a0 = *(const float4*)&Al[k][ty * 8];
    float4 a1 = *(const float4*)&Al[k][ty * 8 + 4];
    float4 b0 = *(const float4*)(bp + (size_t)k * 256);
    float4 b1 = *(const float4*)(bp + (size_t)k * 256 + 4);
    float av[8] = {a0.x, a0.y, a0.z, a0.w, a1.x, a1.y, a1.z, a1.w};
    float bv[8] = {b0.x, b0.y, b0.z, b0.w, b1.x, b1.y, b1.z, b1.w};
#pragma unroll
    for (int r = 0; r < 8; ++r)
#pragma unroll
      for (int c = 0; c < 8; ++c) acc[r][c] = fmaf(av[r], bv[c], acc[r][c]);
  }
#pragma unroll
  for (int r = 0; r < 8; ++r) {
    int row = m0 + ty * 8 + r;
    if (row < M) {
      float4 c0 = make_float4(acc[r][0], acc[r][1], acc[r][2], acc[r][3]);
      float4 c1 = make_float4(acc[r][4], acc[r][5], acc[r][6], acc[r][7]);
      *(float4*)&Cm[(size_t)row * 256 + tx * 8] = c0;
      *(float4*)&Cm[(size_t)row * 256 + tx * 8 + 4] = c1;
    }
  }
}

// ---------------------------------------------------------------- layer-2 head scores
__global__ __launch_bounds__(256) void k_s2(const float* __restrict__ h2, const float* __restrict__ asrc,
                                            const float* __restrict__ adst, float* __restrict__ ssrc,
                                            float* __restrict__ sdst) {
  int n = blockIdx.x, t = threadIdx.x;
  int w = t >> 6, lane = t & 63;
  float v = h2[(size_t)n * 256 + t];
  float ps = v * asrc[t];  // asrc flat [4][64] == [256]
  float pd = v * adst[t];
#pragma unroll
  for (int off = 32; off; off >>= 1) {
    ps += __shfl_xor(ps, off);
    pd += __shfl_xor(pd, off);
  }
  if (lane == 0) { ssrc[n * 4 + w] = ps; sdst[n * 4 + w] = pd; }
}

// ---------------------------------------------------------------- mean pool per graph
__global__ void k_pool(const float* __restrict__ a2, const int* __restrict__ gstart,
                       float* __restrict__ pooled) {
  int g = blockIdx.x;
  int c = blockIdx.y * 64 + threadIdx.x;
  int r0 = gstart[g], r1 = gstart[g + 1];
  float s = 0.f;
  for (int r = r0; r < r1; ++r) s += a2[(size_t)r * 256 + c];
  float cnt = (float)(r1 - r0);
  pooled[g * 256 + c] = s / fmaxf(cnt, 1.0f);
}

// ---------------------------------------------------------------- fused FC head
__global__ __launch_bounds__(256) void k_head(const float* __restrict__ pooled,
                                              const float* __restrict__ w1, const float* __restrict__ b1,
                                              const float* __restrict__ w2, const float* __restrict__ b2,
                                              const float* __restrict__ w3, const float* __restrict__ b3,
                                              float* __restrict__ out) {
  __shared__ float p[256], z1[128], z2[64];
  int g = blockIdx.x, t = threadIdx.x;
  p[t] = pooled[g * 256 + t];
  __syncthreads();
  if (t < 128) {
    float s = b1[t];
    for (int k = 0; k < 256; ++k) s = fmaf(p[k], w1[k * 128 + t], s);
    z1[t] = fmaxf(s, 0.f);
  }
  __syncthreads();
  if (t < 64) {
    float s = b2[t];
    for (int k = 0; k < 128; ++k) s = fmaf(z1[k], w2[k * 64 + t], s);
    z2[t] = fmaxf(s, 0.f);
  }
  __syncthreads();
  if (t < 64) {
    float s = z2[t] * w3[t];
#pragma unroll
    for (int off = 32; off; off >>= 1) s += __shfl_xor(s, off);
    if (t == 0) out[g] = s + b3[0];
  }
}

// ---------------------------------------------------------------- launch
extern "C" void kernel_launch(void* const* d_in, const int* in_sizes, int n_in,
                              void* d_out, int out_size, void* d_ws, size_t ws_size,
                              hipStream_t stream) {
  const float* x    = (const float*)d_in[0];
  const int*   eidx = (const int*)d_in[1];
  const int*   batch= (const int*)d_in[2];
  const float* W1   = (const float*)d_in[3];
  const float* as1  = (const float*)d_in[4];
  const float* ad1  = (const float*)d_in[5];
  const float* b1   = (const float*)d_in[6];
  const float* g1   = (const float*)d_in[7];
  const float* be1  = (const float*)d_in[8];
  const float* W2   = (const float*)d_in[9];
  const float* as2  = (const float*)d_in[10];
  const float* ad2  = (const float*)d_in[11];
  const float* b2   = (const float*)d_in[12];
  const float* g2   = (const float*)d_in[13];
  const float* be2  = (const float*)d_in[14];
  const float* fc1w = (const float*)d_in[15];
  const float* fc1b = (const float*)d_in[16];
  const float* fc2w = (const float*)d_in[17];
  const float* fc2b = (const float*)d_in[18];
  const float* fc3w = (const float*)d_in[19];
  const float* fc3b = (const float*)d_in[20];
  float* out = (float*)d_out;
  (void)n_in; (void)out_size; (void)ws_size;

  int N = in_sizes[0] / 8;
  int E = in_sizes[1] / 2;
  const int* esrc = eidx;
  const int* edst = eidx + E;
  int nchunks = (N + 511) / 512;

  char* w = (char*)d_ws;
  auto take = [&](size_t bytes) -> char* {
    char* r = w;
    w += (bytes + 255) & ~(size_t)255;
    return r;
  };
  int*   offsets = (int*)take(4 * (size_t)(N + 1));
  int*   cursor  = (int*)take(4 * (size_t)N);
  int*   srcs    = (int*)take(4 * (size_t)(E + N));
  int*   partials= (int*)take(4 * (size_t)nchunks);
  int*   gstart  = (int*)take(4 * 65);
  float* bnstat  = (float*)take(4 * 768);
  float* ssrc1   = (float*)take(16 * (size_t)N);
  float* sdst1   = (float*)take(16 * (size_t)N);
  float* ssrc2   = (float*)take(16 * (size_t)N);
  float* sdst2   = (float*)take(16 * (size_t)N);
  float* pooled  = (float*)take(4 * 64 * 256);
  float* regA    = (float*)take(4 * (size_t)N * 256);  // h1 then h2
  float* regB    = (float*)take(4 * (size_t)N * 256);  // out1/a1 then out2/a2

  float* h1 = regA;  float* h2 = regA;
  float* o1 = regB;  float* o2 = regB;
  float* sum1 = bnstat;       float* sq1 = bnstat + 128;
  float* sum2 = bnstat + 256; float* sq2 = bnstat + 512;

  k_init<<<196, 256, 0, stream>>>(cursor, gstart, bnstat, N);
  k_count<<<2048, 256, 0, stream>>>(edst, E, cursor, batch, N, gstart);
  k_scanA<<<nchunks, 512, 0, stream>>>(cursor, N, partials);
  k_scanB<<<1, 1, 0, stream>>>(partials, nchunks, offsets, N, gstart);
  k_scanC<<<nchunks, 512, 0, stream>>>(cursor, offsets, partials, N);
  k_scatter<<<2048, 256, 0, stream>>>(esrc, edst, E, N, cursor, srcs);

  k_h1<<<N, 128, 0, stream>>>(x, W1, as1, ad1, h1, ssrc1, sdst1);
  k_agg<128><<<N, 128, 0, stream>>>(h1, ssrc1, sdst1, offsets, srcs, b1, o1);
  k_bnstats<128><<<256, 128, 0, stream>>>(o1, sum1, sq1, N);
  k_bnapply<128><<<2048, 256, 0, stream>>>(o1, sum1, sq1, g1, be1, N);

  k_gemm2<<<(N + 63) / 64, 256, 0, stream>>>(o1, W2, h2, N);
  k_s2<<<N, 256, 0, stream>>>(h2, as2, ad2, ssrc2, sdst2);
  k_agg<256><<<N, 256, 0, stream>>>(h2, ssrc2, sdst2, offsets, srcs, b2, o2);
  k_bnstats<256><<<256, 256, 0, stream>>>(o2, sum2, sq2, N);
  k_bnapply<256><<<2048, 256, 0, stream>>>(o2, sum2, sq2, g2, be2, N);

  k_pool<<<dim3(64, 4), 64, 0, stream>>>(o2, gstart, pooled);
  k_head<<<64, 256, 0, stream>>>(pooled, fc1w, fc1b, fc2w, fc2b, fc3w, fc3b, out);
}

// Round 2
// 733.800 us; speedup vs baseline: 1.4685x; 1.4685x over previous
//
#include <hip/hip_runtime.h>
#include <cmath>

#define NSLOPE 0.2f
#define BN_EPS 1e-5f

static __device__ __forceinline__ float lrelu(float v) { return v > 0.f ? v : NSLOPE * v; }

// ---------------------------------------------------------------- init
__global__ void k_init(int* __restrict__ cursor, int N) {
  int i = blockIdx.x * blockDim.x + threadIdx.x;
  int stride = gridDim.x * blockDim.x;
  for (int j = i; j < N; j += stride) cursor[j] = 1;  // self-loop count
}

// in-degree histogram (scattered int atomics) + graph starts via sorted-boundary writes
__global__ void k_hist(const int* __restrict__ edst, int E, int* __restrict__ cursor,
                       const int* __restrict__ batch, int N, int* __restrict__ gstart) {
  int i = blockIdx.x * blockDim.x + threadIdx.x;
  int stride = gridDim.x * blockDim.x;
  int total = E > N ? E : N;
  for (int j = i; j < total; j += stride) {
    if (j < E) atomicAdd(&cursor[edst[j]], 1);
    if (j < N) {
      int b = batch[j];
      if (j == 0) {
        for (int g = 0; g <= b; ++g) gstart[g] = 0;
      } else {
        int pb = batch[j - 1];
        if (pb != b)
          for (int g = pb + 1; g <= b; ++g) gstart[g] = j;
      }
      if (j == N - 1)
        for (int g = b + 1; g <= 64; ++g) gstart[g] = N;
    }
  }
}

// ---------------------------------------------------------------- scan (3-phase)
__global__ __launch_bounds__(512) void k_scanA(const int* __restrict__ cnt, int N,
                                               int* __restrict__ partials) {
  int t = threadIdx.x;
  int i = blockIdx.x * 512 + t;
  int v = (i < N) ? cnt[i] : 0;
#pragma unroll
  for (int off = 32; off; off >>= 1) v += __shfl_xor(v, off);
  __shared__ int red[8];
  if ((t & 63) == 0) red[t >> 6] = v;
  __syncthreads();
  if (t == 0) {
    int s = 0;
#pragma unroll
    for (int w = 0; w < 8; ++w) s += red[w];
    partials[blockIdx.x] = s;
  }
}

__global__ void k_scanB(int* __restrict__ partials, int nchunks,
                        int* __restrict__ offsets, int N) {
  if (threadIdx.x == 0 && blockIdx.x == 0) {
    int run = 0;
    for (int b = 0; b < nchunks; ++b) { int t = partials[b]; partials[b] = run; run += t; }
    offsets[N] = run;
  }
}

__global__ __launch_bounds__(512) void k_scanC(int* __restrict__ cursor, int* __restrict__ offsets,
                                               const int* __restrict__ partials, int N) {
  __shared__ int s[512];
  int t = threadIdx.x;
  int i = blockIdx.x * 512 + t;
  int c = (i < N) ? cursor[i] : 0;
  s[t] = c;
  __syncthreads();
  for (int off = 1; off < 512; off <<= 1) {
    int v = (t >= off) ? s[t - off] : 0;
    __syncthreads();
    s[t] += v;
    __syncthreads();
  }
  if (i < N) {
    int excl = s[t] - c + partials[blockIdx.x];
    offsets[i] = excl;
    cursor[i] = excl;  // scatter cursor
  }
}

__global__ void k_scatter(const int* __restrict__ esrc, const int* __restrict__ edst,
                          int E, int N, int* __restrict__ cursor, int* __restrict__ srcs) {
  int i = blockIdx.x * blockDim.x + threadIdx.x;
  int stride = gridDim.x * blockDim.x;
  int total = E + N;
  for (int j = i; j < total; j += stride) {
    int s, d;
    if (j < E) { s = esrc[j]; d = edst[j]; } else { s = j - E; d = j - E; }
    int pos = atomicAdd(&cursor[d], 1);
    srcs[pos] = s;
  }
}

// ---------------------------------------------------------------- layer-1 feature GEMM (K=8) + head scores
__global__ __launch_bounds__(128) void k_h1(const float* __restrict__ x, const float* __restrict__ W,
                                            const float* __restrict__ asrc, const float* __restrict__ adst,
                                            float* __restrict__ h1, float* __restrict__ ssrc,
                                            float* __restrict__ sdst) {
  __shared__ float sx[8];
  int n = blockIdx.x, t = threadIdx.x;
  if (t < 8) sx[t] = x[n * 8 + t];
  __syncthreads();
  float acc = 0.f;
#pragma unroll
  for (int k = 0; k < 8; ++k) acc += sx[k] * W[k * 128 + t];
  h1[(size_t)n * 128 + t] = acc;
  float ps = acc * asrc[t];  // asrc flat [4][32] == [128]
  float pd = acc * adst[t];
#pragma unroll
  for (int off = 16; off; off >>= 1) {
    ps += __shfl_xor(ps, off, 32);
    pd += __shfl_xor(pd, off, 32);
  }
  if ((t & 31) == 0) {
    int h = t >> 5;
    ssrc[n * 4 + h] = ps;
    sdst[n * 4 + h] = pd;
  }
}

// ---------------------------------------------------------------- GAT aggregation (flash-style segment softmax)
template <int F>
__global__ __launch_bounds__(F) void k_agg(const float* __restrict__ hf, const float* __restrict__ ssrc,
                                           const float* __restrict__ sdst, const int* __restrict__ offsets,
                                           const int* __restrict__ srcs, const float* __restrict__ bias,
                                           float* __restrict__ out) {
  constexpr int C = F / 4;
  constexpr int NW = F / 64;
  constexpr int CHUNK = 512;
  __shared__ float4 sc[CHUNK];  // per-edge scores -> exp values (4 heads)
  __shared__ int sidx[CHUNK];   // per-edge src node ids
  __shared__ float red[NW][4];
  __shared__ float mrun[4], drun[4], scA[4];

  int n = blockIdx.x, t = threadIdx.x;
  int head = t / C;
  int wid = t >> 6, lane = t & 63;
  int beg = offsets[n];
  int deg = offsets[n + 1] - beg;

  float4 sd = *(const float4*)&sdst[n * 4];
  if (t < 4) { mrun[t] = -INFINITY; drun[t] = 0.f; }
  __syncthreads();

  float acc0 = 0.f, acc1 = 0.f, acc2 = 0.f, acc3 = 0.f;
  for (int c0 = 0; c0 < deg; c0 += CHUNK) {
    int cn = min(CHUNK, deg - c0);
    int cn4 = (cn + 3) & ~3;
    // phase A: leaky-relu scores + local max; stash src ids in LDS
    float lm0 = -INFINITY, lm1 = -INFINITY, lm2 = -INFINITY, lm3 = -INFINITY;
    for (int e = t; e < cn4; e += F) {
      if (e < cn) {
        int s = srcs[beg + c0 + e];
        sidx[e] = s;
        float4 sv = *(const float4*)&ssrc[s * 4];
        float4 v;
        v.x = lrelu(sv.x + sd.x);
        v.y = lrelu(sv.y + sd.y);
        v.z = lrelu(sv.z + sd.z);
        v.w = lrelu(sv.w + sd.w);
        sc[e] = v;
        lm0 = fmaxf(lm0, v.x); lm1 = fmaxf(lm1, v.y);
        lm2 = fmaxf(lm2, v.z); lm3 = fmaxf(lm3, v.w);
      } else {
        sidx[e] = 0;
      }
    }
#pragma unroll
    for (int off = 32; off; off >>= 1) {
      lm0 = fmaxf(lm0, __shfl_xor(lm0, off));
      lm1 = fmaxf(lm1, __shfl_xor(lm1, off));
      lm2 = fmaxf(lm2, __shfl_xor(lm2, off));
      lm3 = fmaxf(lm3, __shfl_xor(lm3, off));
    }
    if (lane == 0) { red[wid][0] = lm0; red[wid][1] = lm1; red[wid][2] = lm2; red[wid][3] = lm3; }
    __syncthreads();  // B1
    if (t < 4) {
      float mm = red[0][t];
#pragma unroll
      for (int w = 1; w < NW; ++w) mm = fmaxf(mm, red[w][t]);
      float old = mrun[t];
      float mn = fmaxf(old, mm);
      scA[t] = expf(old - mn);  // 0 on first chunk (old = -inf)
      mrun[t] = mn;
    }
    __syncthreads();  // B2
    float m0 = mrun[0], m1 = mrun[1], m2 = mrun[2], m3 = mrun[3];
    // phase A2: exponentiate in place (zero-pad to multiple of 4) + local sums
    float ls0 = 0, ls1 = 0, ls2 = 0, ls3 = 0;
    for (int e = t; e < cn4; e += F) {
      float4 v;
      if (e < cn) {
        v = sc[e];
        v.x = expf(v.x - m0); v.y = expf(v.y - m1);
        v.z = expf(v.z - m2); v.w = expf(v.w - m3);
      } else {
        v = make_float4(0.f, 0.f, 0.f, 0.f);
      }
      sc[e] = v;
      ls0 += v.x; ls1 += v.y; ls2 += v.z; ls3 += v.w;
    }
#pragma unroll
    for (int off = 32; off; off >>= 1) {
      ls0 += __shfl_xor(ls0, off);
      ls1 += __shfl_xor(ls1, off);
      ls2 += __shfl_xor(ls2, off);
      ls3 += __shfl_xor(ls3, off);
    }
    if (lane == 0) { red[wid][0] = ls0; red[wid][1] = ls1; red[wid][2] = ls2; red[wid][3] = ls3; }
    __syncthreads();  // B3
    if (t < 4) {
      float ss = red[0][t];
#pragma unroll
      for (int w = 1; w < NW; ++w) ss += red[w][t];
      drun[t] = drun[t] * scA[t] + ss;
    }
    float sA = scA[head];
    acc0 *= sA; acc1 *= sA; acc2 *= sA; acc3 *= sA;
    // phase B: weighted gather-accumulate, 4 edges in flight
    const float* wvp = (const float*)sc;
    for (int e = 0; e < cn4; e += 4) {
      int s0 = sidx[e + 0], s1 = sidx[e + 1], s2 = sidx[e + 2], s3 = sidx[e + 3];
      float w0 = wvp[(e + 0) * 4 + head];
      float w1 = wvp[(e + 1) * 4 + head];
      float w2 = wvp[(e + 2) * 4 + head];
      float w3 = wvp[(e + 3) * 4 + head];
      acc0 = fmaf(w0, hf[(size_t)s0 * F + t], acc0);
      acc1 = fmaf(w1, hf[(size_t)s1 * F + t], acc1);
      acc2 = fmaf(w2, hf[(size_t)s2 * F + t], acc2);
      acc3 = fmaf(w3, hf[(size_t)s3 * F + t], acc3);
    }
    __syncthreads();  // protect sc/sidx/red before next chunk
  }
  float acc = (acc0 + acc1) + (acc2 + acc3);
  out[(size_t)n * F + t] = acc / drun[head] + bias[t];
}

// ---------------------------------------------------------------- BN stats (partials, no atomics) + reduce + apply(+ELU)
template <int F>
__global__ void k_bnstats(const float* __restrict__ x, float* __restrict__ part, int N) {
  int t = threadIdx.x, b = blockIdx.x;
  float s = 0.f, s2 = 0.f;
  for (int r = b; r < N; r += gridDim.x) {
    float v = x[(size_t)r * F + t];
    s += v; s2 += v * v;
  }
  part[(size_t)b * 2 * F + t] = s;
  part[(size_t)b * 2 * F + F + t] = s2;
}

template <int F>
__global__ void k_bnreduce(const float* __restrict__ part, float* __restrict__ stat) {
  int t = threadIdx.x;  // 2F threads
  float s = 0.f;
  for (int b = 0; b < 128; ++b) s += part[(size_t)b * 2 * F + t];
  stat[t] = s;
}

template <int F>
__global__ void k_bnapply(float* __restrict__ x, const float* __restrict__ sum,
                          const float* __restrict__ sq, const float* __restrict__ gamma,
                          const float* __restrict__ beta, int N) {
  size_t total = (size_t)N * F;
  size_t stride = (size_t)gridDim.x * blockDim.x;
  for (size_t idx = (size_t)blockIdx.x * blockDim.x + threadIdx.x; idx < total; idx += stride) {
    int c = (int)(idx & (F - 1));
    float mean = sum[c] * (1.0f / N);
    float var = sq[c] * (1.0f / N) - mean * mean;
    float inv = rsqrtf(var + BN_EPS);
    float y = gamma[c] * ((x[idx] - mean) * inv) + beta[c];
    x[idx] = y > 0.f ? y : expm1f(y);
  }
}

// ---------------------------------------------------------------- GEMM2: [M,128] @ [128,256], fused layer-2 head scores
__global__ __launch_bounds__(256) void k_gemm2(const float* __restrict__ A,
                                               const float* __restrict__ B,
                                               const float* __restrict__ asrc,
                                               const float* __restrict__ adst,
                                               float* __restrict__ Cm,
                                               float* __restrict__ ssrc,
                                               float* __restrict__ sdst, int M) {
  __shared__ float Al[128][64];  // transposed A tile [k][m]
  int m0 = blockIdx.x * 64;
  int tid = threadIdx.x;
  {
    int ml = tid & 63;
    int kg = tid >> 6;  // 0..3
    int row = m0 + ml;
    const float* arow = A + (size_t)row * 128;
#pragma unroll
    for (int it = 0; it < 8; ++it) {
      int k4 = kg + 4 * it;
      float4 v = make_float4(0.f, 0.f, 0.f, 0.f);
      if (row < M) v = *(const float4*)(arow + k4 * 4);
      Al[k4 * 4 + 0][ml] = v.x;
      Al[k4 * 4 + 1][ml] = v.y;
      Al[k4 * 4 + 2][ml] = v.z;
      Al[k4 * 4 + 3][ml] = v.w;
    }
  }
  __syncthreads();
  int tx = tid & 31, ty = tid >> 5;
  float acc[8][8];
#pragma unroll
  for (int r = 0; r < 8; ++r)
#pragma unroll
    for (int c = 0; c < 8; ++c) acc[r][c] = 0.f;
  const float* bp = B + tx * 8;
#pragma unroll 4
  for (int k = 0; k < 128; ++k) {
    float4 a0 = *(const float4*)&Al[k][ty * 8];
    float4 a1 = *(const float4*)&Al[k][ty * 8 + 4];
    float4 b0 = *(const float4*)(bp + (size_t)k * 256);
    float4 b1 = *(const float4*)(bp + (size_t)k * 256 + 4);
    float av[8] = {a0.x, a0.y, a0.z, a0.w, a1.x, a1.y, a1.z, a1.w};
    float bv[8] = {b0.x, b0.y, b0.z, b0.w, b1.x, b1.y, b1.z, b1.w};
#pragma unroll
    for (int r = 0; r < 8; ++r)
#pragma unroll
      for (int c = 0; c < 8; ++c) acc[r][c] = fmaf(av[r], bv[c], acc[r][c]);
  }
#pragma unroll
  for (int r = 0; r < 8; ++r) {
    int row = m0 + ty * 8 + r;
    if (row < M) {
      float4 c0 = make_float4(acc[r][0], acc[r][1], acc[r][2], acc[r][3]);
      float4 c1 = make_float4(acc[r][4], acc[r][5], acc[r][6], acc[r][7]);
      *(float4*)&Cm[(size_t)row * 256 + tx * 8] = c0;
      *(float4*)&Cm[(size_t)row * 256 + tx * 8 + 4] = c1;
    }
  }
  // fused per-head attention scores: thread's 8 cols all lie in head tx>>3
  float asv[8], adv[8];
#pragma unroll
  for (int c = 0; c < 8; ++c) { asv[c] = asrc[tx * 8 + c]; adv[c] = adst[tx * 8 + c]; }
#pragma unroll
  for (int r = 0; r < 8; ++r) {
    float ps = 0.f, pd = 0.f;
#pragma unroll
    for (int c = 0; c < 8; ++c) { ps = fmaf(acc[r][c], asv[c], ps); pd = fmaf(acc[r][c], adv[c], pd); }
#pragma unroll
    for (int off = 1; off < 8; off <<= 1) { ps += __shfl_xor(ps, off); pd += __shfl_xor(pd, off); }
    int row = m0 + ty * 8 + r;
    if ((tx & 7) == 0 && row < M) {
      int h = tx >> 3;
      ssrc[row * 4 + h] = ps;
      sdst[row * 4 + h] = pd;
    }
  }
}

// ---------------------------------------------------------------- mean pool partials per (graph, chunk)
__global__ __launch_bounds__(256) void k_poolpart(const float* __restrict__ a2,
                                                  const int* __restrict__ gstart,
                                                  float* __restrict__ part) {
  int g = blockIdx.x, by = blockIdx.y, t = threadIdx.x;
  int r0 = gstart[g], r1 = gstart[g + 1];
  float s = 0.f;
  for (int base = r0 + by * 128; base < r1; base += 16 * 128) {
    int lim = min(r1, base + 128);
    for (int r = base; r < lim; ++r) s += a2[(size_t)r * 256 + t];
  }
  part[((size_t)g * 16 + by) * 256 + t] = s;
}

// ---------------------------------------------------------------- fused FC head (+ pool reduce/divide)
__global__ __launch_bounds__(256) void k_head(const float* __restrict__ poolpart,
                                              const int* __restrict__ gstart,
                                              const float* __restrict__ w1, const float* __restrict__ b1,
                                              const float* __restrict__ w2, const float* __restrict__ b2,
                                              const float* __restrict__ w3, const float* __restrict__ b3,
                                              float* __restrict__ out) {
  __shared__ float p[256], z1[128], z2[64];
  int g = blockIdx.x, t = threadIdx.x;
  float s0 = 0.f;
#pragma unroll
  for (int b = 0; b < 16; ++b) s0 += poolpart[((size_t)g * 16 + b) * 256 + t];
  float cnt = (float)(gstart[g + 1] - gstart[g]);
  p[t] = s0 / fmaxf(cnt, 1.0f);
  __syncthreads();
  if (t < 128) {
    float s = b1[t];
    for (int k = 0; k < 256; ++k) s = fmaf(p[k], w1[k * 128 + t], s);
    z1[t] = fmaxf(s, 0.f);
  }
  __syncthreads();
  if (t < 64) {
    float s = b2[t];
    for (int k = 0; k < 128; ++k) s = fmaf(z1[k], w2[k * 64 + t], s);
    z2[t] = fmaxf(s, 0.f);
  }
  __syncthreads();
  if (t < 64) {
    float s = z2[t] * w3[t];
#pragma unroll
    for (int off = 32; off; off >>= 1) s += __shfl_xor(s, off);
    if (t == 0) out[g] = s + b3[0];
  }
}

// ---------------------------------------------------------------- launch
extern "C" void kernel_launch(void* const* d_in, const int* in_sizes, int n_in,
                              void* d_out, int out_size, void* d_ws, size_t ws_size,
                              hipStream_t stream) {
  const float* x    = (const float*)d_in[0];
  const int*   eidx = (const int*)d_in[1];
  const int*   batch= (const int*)d_in[2];
  const float* W1   = (const float*)d_in[3];
  const float* as1  = (const float*)d_in[4];
  const float* ad1  = (const float*)d_in[5];
  const float* b1   = (const float*)d_in[6];
  const float* g1   = (const float*)d_in[7];
  const float* be1  = (const float*)d_in[8];
  const float* W2   = (const float*)d_in[9];
  const float* as2  = (const float*)d_in[10];
  const float* ad2  = (const float*)d_in[11];
  const float* b2   = (const float*)d_in[12];
  const float* g2   = (const float*)d_in[13];
  const float* be2  = (const float*)d_in[14];
  const float* fc1w = (const float*)d_in[15];
  const float* fc1b = (const float*)d_in[16];
  const float* fc2w = (const float*)d_in[17];
  const float* fc2b = (const float*)d_in[18];
  const float* fc3w = (const float*)d_in[19];
  const float* fc3b = (const float*)d_in[20];
  float* out = (float*)d_out;
  (void)n_in; (void)out_size; (void)ws_size;

  int N = in_sizes[0] / 8;
  int E = in_sizes[1] / 2;
  const int* esrc = eidx;
  const int* edst = eidx + E;
  int nchunks = (N + 511) / 512;

  char* w = (char*)d_ws;
  auto take = [&](size_t bytes) -> char* {
    char* r = w;
    w += (bytes + 255) & ~(size_t)255;
    return r;
  };
  int*   offsets = (int*)take(4 * (size_t)(N + 1));
  int*   cursor  = (int*)take(4 * (size_t)N);
  int*   srcs    = (int*)take(4 * (size_t)(E + N));
  int*   partials= (int*)take(4 * (size_t)nchunks);
  int*   gstart  = (int*)take(4 * 65);
  float* bnstat  = (float*)take(4 * 768);
  float* bnpart  = (float*)take(4 * 128 * 512);
  float* poolpart= (float*)take(4 * 64 * 16 * 256);
  float* ssrc1   = (float*)take(16 * (size_t)N);
  float* sdst1   = (float*)take(16 * (size_t)N);
  float* ssrc2   = (float*)take(16 * (size_t)N);
  float* sdst2   = (float*)take(16 * (size_t)N);
  float* regA    = (float*)take(4 * (size_t)N * 256);  // h1 then h2
  float* regB    = (float*)take(4 * (size_t)N * 256);  // out1/a1 then out2/a2

  float* h1 = regA;  float* h2 = regA;
  float* o1 = regB;  float* o2 = regB;
  float* sum1 = bnstat;       float* sq1 = bnstat + 128;
  float* sum2 = bnstat + 256; float* sq2 = bnstat + 512;

  k_init<<<196, 256, 0, stream>>>(cursor, N);
  k_hist<<<2048, 256, 0, stream>>>(edst, E, cursor, batch, N, gstart);
  k_scanA<<<nchunks, 512, 0, stream>>>(cursor, N, partials);
  k_scanB<<<1, 1, 0, stream>>>(partials, nchunks, offsets, N);
  k_scanC<<<nchunks, 512, 0, stream>>>(cursor, offsets, partials, N);
  k_scatter<<<2048, 256, 0, stream>>>(esrc, edst, E, N, cursor, srcs);

  k_h1<<<N, 128, 0, stream>>>(x, W1, as1, ad1, h1, ssrc1, sdst1);
  k_agg<128><<<N, 128, 0, stream>>>(h1, ssrc1, sdst1, offsets, srcs, b1, o1);
  k_bnstats<128><<<128, 128, 0, stream>>>(o1, bnpart, N);
  k_bnreduce<128><<<1, 256, 0, stream>>>(bnpart, bnstat);
  k_bnapply<128><<<2048, 256, 0, stream>>>(o1, sum1, sq1, g1, be1, N);

  k_gemm2<<<(N + 63) / 64, 256, 0, stream>>>(o1, W2, as2, ad2, h2, ssrc2, sdst2, N);
  k_agg<256><<<N, 256, 0, stream>>>(h2, ssrc2, sdst2, offsets, srcs, b2, o2);
  k_bnstats<256><<<128, 256, 0, stream>>>(o2, bnpart, N);
  k_bnreduce<256><<<1, 512, 0, stream>>>(bnpart, bnstat + 256);
  k_bnapply<256><<<2048, 256, 0, stream>>>(o2, sum2, sq2, g2, be2, N);

  k_poolpart<<<dim3(64, 16), 256, 0, stream>>>(o2, gstart, poolpart);
  k_head<<<64, 256, 0, stream>>>(poolpart, gstart, fc1w, fc1b, fc2w, fc2b, fc3w, fc3b, out);
}

// Round 3
// 684.872 us; speedup vs baseline: 1.5734x; 1.0714x over previous
//
#include <hip/hip_runtime.h>
#include <cmath>

#define NSLOPE 0.2f
#define BN_EPS 1e-5f

static __device__ __forceinline__ float lrelu(float v) { return v > 0.f ? v : NSLOPE * v; }

// ---------------------------------------------------------------- init
__global__ void k_init(int* __restrict__ cursor, int N) {
  int i = blockIdx.x * blockDim.x + threadIdx.x;
  int stride = gridDim.x * blockDim.x;
  for (int j = i; j < N; j += stride) cursor[j] = 1;  // self-loop count
}

// in-degree histogram + graph starts via sorted-boundary writes
__global__ void k_hist(const int* __restrict__ edst, int E, int* __restrict__ cursor,
                       const int* __restrict__ batch, int N, int* __restrict__ gstart) {
  int i = blockIdx.x * blockDim.x + threadIdx.x;
  int stride = gridDim.x * blockDim.x;
  int total = E > N ? E : N;
  for (int j = i; j < total; j += stride) {
    if (j < E) atomicAdd(&cursor[edst[j]], 1);
    if (j < N) {
      int b = batch[j];
      if (j == 0) {
        for (int g = 0; g <= b; ++g) gstart[g] = 0;
      } else {
        int pb = batch[j - 1];
        if (pb != b)
          for (int g = pb + 1; g <= b; ++g) gstart[g] = j;
      }
      if (j == N - 1)
        for (int g = b + 1; g <= 64; ++g) gstart[g] = N;
    }
  }
}

// ---------------------------------------------------------------- scan (3-phase)
__global__ __launch_bounds__(512) void k_scanA(const int* __restrict__ cnt, int N,
                                               int* __restrict__ partials) {
  int t = threadIdx.x;
  int i = blockIdx.x * 512 + t;
  int v = (i < N) ? cnt[i] : 0;
#pragma unroll
  for (int off = 32; off; off >>= 1) v += __shfl_xor(v, off);
  __shared__ int red[8];
  if ((t & 63) == 0) red[t >> 6] = v;
  __syncthreads();
  if (t == 0) {
    int s = 0;
#pragma unroll
    for (int w = 0; w < 8; ++w) s += red[w];
    partials[blockIdx.x] = s;
  }
}

__global__ void k_scanB(int* __restrict__ partials, int nchunks,
                        int* __restrict__ offsets, int N) {
  if (threadIdx.x == 0 && blockIdx.x == 0) {
    int run = 0;
    for (int b = 0; b < nchunks; ++b) { int t = partials[b]; partials[b] = run; run += t; }
    offsets[N] = run;
  }
}

__global__ __launch_bounds__(512) void k_scanC(int* __restrict__ cursor, int* __restrict__ offsets,
                                               const int* __restrict__ partials, int N) {
  __shared__ int s[512];
  int t = threadIdx.x;
  int i = blockIdx.x * 512 + t;
  int c = (i < N) ? cursor[i] : 0;
  s[t] = c;
  __syncthreads();
  for (int off = 1; off < 512; off <<= 1) {
    int v = (t >= off) ? s[t - off] : 0;
    __syncthreads();
    s[t] += v;
    __syncthreads();
  }
  if (i < N) {
    int excl = s[t] - c + partials[blockIdx.x];
    offsets[i] = excl;
    cursor[i] = excl;  // scatter cursor
  }
}

__global__ void k_scatter(const int* __restrict__ esrc, const int* __restrict__ edst,
                          int E, int N, int* __restrict__ cursor, int* __restrict__ srcs) {
  int i = blockIdx.x * blockDim.x + threadIdx.x;
  int stride = gridDim.x * blockDim.x;
  int total = E + N;
  for (int j = i; j < total; j += stride) {
    int s, d;
    if (j < E) { s = esrc[j]; d = edst[j]; } else { s = j - E; d = j - E; }
    int pos = atomicAdd(&cursor[d], 1);
    srcs[pos] = s;
  }
}

// ---------------------------------------------------------------- q = W @ a  (per-head projected score vectors)
__global__ void k_prep(const float* __restrict__ W1, const float* __restrict__ as1,
                       const float* __restrict__ ad1, const float* __restrict__ W2,
                       const float* __restrict__ as2, const float* __restrict__ ad2,
                       float* __restrict__ q1s, float* __restrict__ q1d,
                       float* __restrict__ q2s, float* __restrict__ q2d) {
  int t = threadIdx.x;
  if (t < 32) {  // q1[k][h], k<8, h<4
    int k = t >> 2, h = t & 3;
    float s = 0.f, d = 0.f;
    for (int c = 0; c < 32; ++c) {
      float w = W1[k * 128 + h * 32 + c];
      s = fmaf(w, as1[h * 32 + c], s);
      d = fmaf(w, ad1[h * 32 + c], d);
    }
    q1s[t] = s; q1d[t] = d;
  }
  for (int i = t; i < 512; i += 256) {  // q2[k][h], k<128, h<4
    int k = i >> 2, h = i & 3;
    float s = 0.f, d = 0.f;
    for (int c = 0; c < 64; ++c) {
      float w = W2[k * 256 + h * 64 + c];
      s = fmaf(w, as2[h * 64 + c], s);
      d = fmaf(w, ad2[h * 64 + c], d);
    }
    q2s[i] = s; q2d[i] = d;
  }
}

// ---------------------------------------------------------------- layer-1 scores from x
__global__ __launch_bounds__(256) void k_s1(const float* __restrict__ x,
                                            const float* __restrict__ q1s,
                                            const float* __restrict__ q1d,
                                            float* __restrict__ ssrc, float* __restrict__ sdst,
                                            int N) {
  __shared__ float qs[32], qd[32];
  int t = threadIdx.x;
  if (t < 32) { qs[t] = q1s[t]; qd[t] = q1d[t]; }
  __syncthreads();
  for (int n = blockIdx.x * 256 + t; n < N; n += gridDim.x * 256) {
    float4 x0 = *(const float4*)&x[n * 8];
    float4 x1 = *(const float4*)&x[n * 8 + 4];
    float xs[8] = {x0.x, x0.y, x0.z, x0.w, x1.x, x1.y, x1.z, x1.w};
    float4 rs = make_float4(0.f, 0.f, 0.f, 0.f);
    float4 rd = make_float4(0.f, 0.f, 0.f, 0.f);
#pragma unroll
    for (int k = 0; k < 8; ++k) {
      rs.x = fmaf(xs[k], qs[k * 4 + 0], rs.x);
      rs.y = fmaf(xs[k], qs[k * 4 + 1], rs.y);
      rs.z = fmaf(xs[k], qs[k * 4 + 2], rs.z);
      rs.w = fmaf(xs[k], qs[k * 4 + 3], rs.w);
      rd.x = fmaf(xs[k], qd[k * 4 + 0], rd.x);
      rd.y = fmaf(xs[k], qd[k * 4 + 1], rd.y);
      rd.z = fmaf(xs[k], qd[k * 4 + 2], rd.z);
      rd.w = fmaf(xs[k], qd[k * 4 + 3], rd.w);
    }
    *(float4*)&ssrc[n * 4] = rs;
    *(float4*)&sdst[n * 4] = rd;
  }
}

// ---------------------------------------------------------------- layer-1 aggregation in x-space (32B/edge gather)
__global__ __launch_bounds__(64) void k_agg1(const float* __restrict__ x,
                                             const float* __restrict__ ssrc,
                                             const float* __restrict__ sdst,
                                             const int* __restrict__ offsets,
                                             const int* __restrict__ srcs,
                                             float* __restrict__ agg /*[N][4][8]*/) {
  constexpr int CHUNK = 256;
  __shared__ float4 sc[CHUNK];
  __shared__ int sidx[CHUNK];
  __shared__ float mrun[4], drun[4], scA[4];
  int n = blockIdx.x, t = threadIdx.x;
  int k = t & 7, es = t >> 3;  // feature, edge-slot
  int beg = offsets[n], deg = offsets[n + 1] - beg;
  float4 sd = *(const float4*)&sdst[n * 4];
  if (t < 4) { mrun[t] = -INFINITY; drun[t] = 0.f; }
  __syncthreads();
  float a0 = 0.f, a1v = 0.f, a2v = 0.f, a3v = 0.f;
  for (int c0 = 0; c0 < deg; c0 += CHUNK) {
    int cn = min(CHUNK, deg - c0);
    int cn8 = (cn + 7) & ~7;
    float lm0 = -INFINITY, lm1 = -INFINITY, lm2 = -INFINITY, lm3 = -INFINITY;
    for (int e = t; e < cn8; e += 64) {
      if (e < cn) {
        int s = srcs[beg + c0 + e];
        sidx[e] = s;
        float4 sv = *(const float4*)&ssrc[s * 4];
        float4 v;
        v.x = lrelu(sv.x + sd.x);
        v.y = lrelu(sv.y + sd.y);
        v.z = lrelu(sv.z + sd.z);
        v.w = lrelu(sv.w + sd.w);
        sc[e] = v;
        lm0 = fmaxf(lm0, v.x); lm1 = fmaxf(lm1, v.y);
        lm2 = fmaxf(lm2, v.z); lm3 = fmaxf(lm3, v.w);
      } else {
        sidx[e] = 0;
      }
    }
#pragma unroll
    for (int off = 32; off; off >>= 1) {
      lm0 = fmaxf(lm0, __shfl_xor(lm0, off));
      lm1 = fmaxf(lm1, __shfl_xor(lm1, off));
      lm2 = fmaxf(lm2, __shfl_xor(lm2, off));
      lm3 = fmaxf(lm3, __shfl_xor(lm3, off));
    }
    if (t == 0) {
      float o, m;
      o = mrun[0]; m = fmaxf(o, lm0); scA[0] = expf(o - m); mrun[0] = m;
      o = mrun[1]; m = fmaxf(o, lm1); scA[1] = expf(o - m); mrun[1] = m;
      o = mrun[2]; m = fmaxf(o, lm2); scA[2] = expf(o - m); mrun[2] = m;
      o = mrun[3]; m = fmaxf(o, lm3); scA[3] = expf(o - m); mrun[3] = m;
    }
    __syncthreads();
    float m0 = mrun[0], m1 = mrun[1], m2 = mrun[2], m3 = mrun[3];
    float ls0 = 0.f, ls1 = 0.f, ls2 = 0.f, ls3 = 0.f;
    for (int e = t; e < cn8; e += 64) {
      float4 v;
      if (e < cn) {
        v = sc[e];
        v.x = expf(v.x - m0); v.y = expf(v.y - m1);
        v.z = expf(v.z - m2); v.w = expf(v.w - m3);
      } else {
        v = make_float4(0.f, 0.f, 0.f, 0.f);
      }
      sc[e] = v;
      ls0 += v.x; ls1 += v.y; ls2 += v.z; ls3 += v.w;
    }
#pragma unroll
    for (int off = 32; off; off >>= 1) {
      ls0 += __shfl_xor(ls0, off); ls1 += __shfl_xor(ls1, off);
      ls2 += __shfl_xor(ls2, off); ls3 += __shfl_xor(ls3, off);
    }
    if (t == 0) {
      drun[0] = drun[0] * scA[0] + ls0;
      drun[1] = drun[1] * scA[1] + ls1;
      drun[2] = drun[2] * scA[2] + ls2;
      drun[3] = drun[3] * scA[3] + ls3;
    }
    __syncthreads();
    float sA0 = scA[0], sA1 = scA[1], sA2 = scA[2], sA3 = scA[3];
    a0 *= sA0; a1v *= sA1; a2v *= sA2; a3v *= sA3;
    for (int e = es; e < cn8; e += 8) {
      int s = sidx[e];
      float v = x[s * 8 + k];
      float4 w = sc[e];
      a0 = fmaf(w.x, v, a0); a1v = fmaf(w.y, v, a1v);
      a2v = fmaf(w.z, v, a2v); a3v = fmaf(w.w, v, a3v);
    }
    __syncthreads();
  }
#pragma unroll
  for (int off = 8; off < 64; off <<= 1) {
    a0 += __shfl_xor(a0, off); a1v += __shfl_xor(a1v, off);
    a2v += __shfl_xor(a2v, off); a3v += __shfl_xor(a3v, off);
  }
  if (es == 0) {
    agg[n * 32 + 0 + k]  = a0 / drun[0];
    agg[n * 32 + 8 + k]  = a1v / drun[1];
    agg[n * 32 + 16 + k] = a2v / drun[2];
    agg[n * 32 + 24 + k] = a3v / drun[3];
  }
}

// ---------------------------------------------------------------- out1 = agg1 @ W1 (per head) + b1
__global__ __launch_bounds__(128) void k_post1(const float* __restrict__ agg,
                                               const float* __restrict__ W1,
                                               const float* __restrict__ b1,
                                               float* __restrict__ o1, int N) {
  int t = threadIdx.x;
  __shared__ float ag[32];
  float bb = b1[t];
  float wc[8];
#pragma unroll
  for (int k = 0; k < 8; ++k) wc[k] = W1[k * 128 + t];
  int h = t >> 5;
  for (int n = blockIdx.x; n < N; n += gridDim.x) {
    if (t < 32) ag[t] = agg[n * 32 + t];
    __syncthreads();
    float s = bb;
#pragma unroll
    for (int k = 0; k < 8; ++k) s = fmaf(ag[h * 8 + k], wc[k], s);
    o1[(size_t)n * 128 + t] = s;
    __syncthreads();
  }
}

// ---------------------------------------------------------------- BN stats (partials) + reduce
template <int F>
__global__ void k_bnstats(const float* __restrict__ x, float* __restrict__ part, int N) {
  int t = threadIdx.x, b = blockIdx.x;
  float s = 0.f, s2 = 0.f;
  for (int r = b; r < N; r += gridDim.x) {
    float v = x[(size_t)r * F + t];
    s += v; s2 += v * v;
  }
  part[(size_t)b * 2 * F + t] = s;
  part[(size_t)b * 2 * F + F + t] = s2;
}

template <int F>
__global__ void k_bnreduce(const float* __restrict__ part, float* __restrict__ stat) {
  int t = threadIdx.x;  // 2F threads
  float s = 0.f;
  for (int b = 0; b < 128; ++b) s += part[(size_t)b * 2 * F + t];
  stat[t] = s;
}

// ---------------------------------------------------------------- BN1 apply + ELU + fused layer-2 scores
__global__ __launch_bounds__(128) void k_bns2(float* __restrict__ xio,
                                              const float* __restrict__ sum,
                                              const float* __restrict__ sq,
                                              const float* __restrict__ gamma,
                                              const float* __restrict__ beta,
                                              const float* __restrict__ q2s,
                                              const float* __restrict__ q2d,
                                              float* __restrict__ ssrc2,
                                              float* __restrict__ sdst2, int N) {
  int t = threadIdx.x;
  float mean = sum[t] * (1.0f / N);
  float var = sq[t] * (1.0f / N) - mean * mean;
  float inv = rsqrtf(var + BN_EPS);
  float ga = gamma[t], be = beta[t];
  float4 qs = *(const float4*)&q2s[t * 4];
  float4 qd = *(const float4*)&q2d[t * 4];
  __shared__ float redv[2][8];
  int wid = t >> 6, lane = t & 63;
  for (int r = blockIdx.x; r < N; r += gridDim.x) {
    float v = xio[(size_t)r * 128 + t];
    float y = ga * ((v - mean) * inv) + be;
    y = y > 0.f ? y : expm1f(y);
    xio[(size_t)r * 128 + t] = y;
    float p0 = y * qs.x, p1 = y * qs.y, p2 = y * qs.z, p3 = y * qs.w;
    float d0 = y * qd.x, d1 = y * qd.y, d2 = y * qd.z, d3 = y * qd.w;
#pragma unroll
    for (int off = 32; off; off >>= 1) {
      p0 += __shfl_xor(p0, off); p1 += __shfl_xor(p1, off);
      p2 += __shfl_xor(p2, off); p3 += __shfl_xor(p3, off);
      d0 += __shfl_xor(d0, off); d1 += __shfl_xor(d1, off);
      d2 += __shfl_xor(d2, off); d3 += __shfl_xor(d3, off);
    }
    if (lane == 0) {
      redv[wid][0] = p0; redv[wid][1] = p1; redv[wid][2] = p2; redv[wid][3] = p3;
      redv[wid][4] = d0; redv[wid][5] = d1; redv[wid][6] = d2; redv[wid][7] = d3;
    }
    __syncthreads();
    if (t < 8) {
      float s = redv[0][t] + redv[1][t];
      if (t < 4) ssrc2[r * 4 + t] = s;
      else sdst2[r * 4 + (t - 4)] = s;
    }
    __syncthreads();
  }
}

// ---------------------------------------------------------------- layer-2 aggregation in a1-space (512B/edge gather)
__global__ __launch_bounds__(128) void k_agg2(const float* __restrict__ a1,
                                              const float* __restrict__ ssrc,
                                              const float* __restrict__ sdst,
                                              const int* __restrict__ offsets,
                                              const int* __restrict__ srcs,
                                              float* __restrict__ agg /*[4][N][128]*/, int N) {
  constexpr int CHUNK = 512;
  __shared__ float4 sc[CHUNK];
  __shared__ int sidx[CHUNK];
  __shared__ float red[2][4];
  __shared__ float mrun[4], drun[4], scA[4];
  int n = blockIdx.x, t = threadIdx.x;
  int wid = t >> 6, lane = t & 63;
  int beg = offsets[n], deg = offsets[n + 1] - beg;
  float4 sd = *(const float4*)&sdst[n * 4];
  if (t < 4) { mrun[t] = -INFINITY; drun[t] = 0.f; }
  __syncthreads();
  float aA0 = 0.f, aA1 = 0.f, aA2 = 0.f, aA3 = 0.f;
  float aB0 = 0.f, aB1 = 0.f, aB2 = 0.f, aB3 = 0.f;
  for (int c0 = 0; c0 < deg; c0 += CHUNK) {
    int cn = min(CHUNK, deg - c0);
    int cn4 = (cn + 3) & ~3;
    float lm0 = -INFINITY, lm1 = -INFINITY, lm2 = -INFINITY, lm3 = -INFINITY;
    for (int e = t; e < cn4; e += 128) {
      if (e < cn) {
        int s = srcs[beg + c0 + e];
        sidx[e] = s;
        float4 sv = *(const float4*)&ssrc[s * 4];
        float4 v;
        v.x = lrelu(sv.x + sd.x);
        v.y = lrelu(sv.y + sd.y);
        v.z = lrelu(sv.z + sd.z);
        v.w = lrelu(sv.w + sd.w);
        sc[e] = v;
        lm0 = fmaxf(lm0, v.x); lm1 = fmaxf(lm1, v.y);
        lm2 = fmaxf(lm2, v.z); lm3 = fmaxf(lm3, v.w);
      } else {
        sidx[e] = 0;
      }
    }
#pragma unroll
    for (int off = 32; off; off >>= 1) {
      lm0 = fmaxf(lm0, __shfl_xor(lm0, off));
      lm1 = fmaxf(lm1, __shfl_xor(lm1, off));
      lm2 = fmaxf(lm2, __shfl_xor(lm2, off));
      lm3 = fmaxf(lm3, __shfl_xor(lm3, off));
    }
    if (lane == 0) { red[wid][0] = lm0; red[wid][1] = lm1; red[wid][2] = lm2; red[wid][3] = lm3; }
    __syncthreads();
    if (t < 4) {
      float mm = fmaxf(red[0][t], red[1][t]);
      float old = mrun[t];
      float mn = fmaxf(old, mm);
      scA[t] = expf(old - mn);
      mrun[t] = mn;
    }
    __syncthreads();
    float m0 = mrun[0], m1 = mrun[1], m2 = mrun[2], m3 = mrun[3];
    float ls0 = 0.f, ls1 = 0.f, ls2 = 0.f, ls3 = 0.f;
    for (int e = t; e < cn4; e += 128) {
      float4 v;
      if (e < cn) {
        v = sc[e];
        v.x = expf(v.x - m0); v.y = expf(v.y - m1);
        v.z = expf(v.z - m2); v.w = expf(v.w - m3);
      } else {
        v = make_float4(0.f, 0.f, 0.f, 0.f);
      }
      sc[e] = v;
      ls0 += v.x; ls1 += v.y; ls2 += v.z; ls3 += v.w;
    }
#pragma unroll
    for (int off = 32; off; off >>= 1) {
      ls0 += __shfl_xor(ls0, off); ls1 += __shfl_xor(ls1, off);
      ls2 += __shfl_xor(ls2, off); ls3 += __shfl_xor(ls3, off);
    }
    if (lane == 0) { red[wid][0] = ls0; red[wid][1] = ls1; red[wid][2] = ls2; red[wid][3] = ls3; }
    __syncthreads();
    if (t < 4) drun[t] = drun[t] * scA[t] + (red[0][t] + red[1][t]);
    float sA0 = scA[0], sA1 = scA[1], sA2 = scA[2], sA3 = scA[3];
    aA0 *= sA0; aB0 *= sA0; aA1 *= sA1; aB1 *= sA1;
    aA2 *= sA2; aB2 *= sA2; aA3 *= sA3; aB3 *= sA3;
    for (int e = 0; e < cn4; e += 4) {
      int i0 = sidx[e], i1 = sidx[e + 1], i2 = sidx[e + 2], i3 = sidx[e + 3];
      float v0 = a1[(size_t)i0 * 128 + t];
      float v1 = a1[(size_t)i1 * 128 + t];
      float v2 = a1[(size_t)i2 * 128 + t];
      float v3 = a1[(size_t)i3 * 128 + t];
      float4 w0 = sc[e], w1 = sc[e + 1], w2 = sc[e + 2], w3 = sc[e + 3];
      aA0 = fmaf(w0.x, v0, aA0); aA1 = fmaf(w0.y, v0, aA1);
      aA2 = fmaf(w0.z, v0, aA2); aA3 = fmaf(w0.w, v0, aA3);
      aB0 = fmaf(w1.x, v1, aB0); aB1 = fmaf(w1.y, v1, aB1);
      aB2 = fmaf(w1.z, v1, aB2); aB3 = fmaf(w1.w, v1, aB3);
      aA0 = fmaf(w2.x, v2, aA0); aA1 = fmaf(w2.y, v2, aA1);
      aA2 = fmaf(w2.z, v2, aA2); aA3 = fmaf(w2.w, v2, aA3);
      aB0 = fmaf(w3.x, v3, aB0); aB1 = fmaf(w3.y, v3, aB1);
      aB2 = fmaf(w3.z, v3, aB2); aB3 = fmaf(w3.w, v3, aB3);
    }
    __syncthreads();
  }
  size_t nn = (size_t)n * 128 + t;
  size_t pl = (size_t)N * 128;
  agg[nn] = (aA0 + aB0) / drun[0];
  agg[pl + nn] = (aA1 + aB1) / drun[1];
  agg[2 * pl + nn] = (aA2 + aB2) / drun[2];
  agg[3 * pl + nn] = (aA3 + aB3) / drun[3];
}

// ---------------------------------------------------------------- out2 = per-head [N,128]@[128,64] + b2
__global__ __launch_bounds__(256) void k_post2(const float* __restrict__ agg,
                                               const float* __restrict__ W2,
                                               const float* __restrict__ b2,
                                               float* __restrict__ out, int N) {
  __shared__ float As[128][64];
  __shared__ float Bs[128][64];
  int h = blockIdx.y;
  int m0 = blockIdx.x * 64;
  int tid = threadIdx.x;
  const float* Ap = agg + (size_t)h * N * 128;
  {
    int ml = tid & 63, kg = tid >> 6;
    const float* arow = Ap + (size_t)(m0 + ml) * 128;
    bool rok = (m0 + ml) < N;
#pragma unroll
    for (int it = 0; it < 8; ++it) {
      int k4 = kg + 4 * it;
      float4 v = rok ? *(const float4*)(arow + k4 * 4) : make_float4(0.f, 0.f, 0.f, 0.f);
      As[k4 * 4 + 0][ml] = v.x;
      As[k4 * 4 + 1][ml] = v.y;
      As[k4 * 4 + 2][ml] = v.z;
      As[k4 * 4 + 3][ml] = v.w;
    }
  }
  {
    int c4 = tid & 15, k0 = tid >> 4;  // 16 row-groups
    for (int k = k0; k < 128; k += 16) {
      float4 v = *(const float4*)&W2[(size_t)k * 256 + h * 64 + c4 * 4];
      *(float4*)&Bs[k][c4 * 4] = v;
    }
  }
  __syncthreads();
  int tx = tid & 15, ty = tid >> 4;
  float acc[4][4];
#pragma unroll
  for (int r = 0; r < 4; ++r)
#pragma unroll
    for (int c = 0; c < 4; ++c) acc[r][c] = 0.f;
#pragma unroll 2
  for (int k = 0; k < 128; ++k) {
    float4 a4 = *(const float4*)&As[k][ty * 4];
    float4 b4 = *(const float4*)&Bs[k][tx * 4];
    float av[4] = {a4.x, a4.y, a4.z, a4.w};
    float bv[4] = {b4.x, b4.y, b4.z, b4.w};
#pragma unroll
    for (int r = 0; r < 4; ++r)
#pragma unroll
      for (int c = 0; c < 4; ++c) acc[r][c] = fmaf(av[r], bv[c], acc[r][c]);
  }
  float4 bb = *(const float4*)&b2[h * 64 + tx * 4];
#pragma unroll
  for (int r = 0; r < 4; ++r) {
    int row = m0 + ty * 4 + r;
    if (row < N) {
      float4 c4;
      c4.x = acc[r][0] + bb.x; c4.y = acc[r][1] + bb.y;
      c4.z = acc[r][2] + bb.z; c4.w = acc[r][3] + bb.w;
      *(float4*)&out[(size_t)row * 256 + h * 64 + tx * 4] = c4;
    }
  }
}

// ---------------------------------------------------------------- BN apply + ELU (elementwise)
template <int F>
__global__ void k_bnapply(float* __restrict__ x, const float* __restrict__ sum,
                          const float* __restrict__ sq, const float* __restrict__ gamma,
                          const float* __restrict__ beta, int N) {
  size_t total = (size_t)N * F;
  size_t stride = (size_t)gridDim.x * blockDim.x;
  for (size_t idx = (size_t)blockIdx.x * blockDim.x + threadIdx.x; idx < total; idx += stride) {
    int c = (int)(idx & (F - 1));
    float mean = sum[c] * (1.0f / N);
    float var = sq[c] * (1.0f / N) - mean * mean;
    float inv = rsqrtf(var + BN_EPS);
    float y = gamma[c] * ((x[idx] - mean) * inv) + beta[c];
    x[idx] = y > 0.f ? y : expm1f(y);
  }
}

// ---------------------------------------------------------------- mean pool partials per (graph, chunk)
__global__ __launch_bounds__(256) void k_poolpart(const float* __restrict__ a2,
                                                  const int* __restrict__ gstart,
                                                  float* __restrict__ part) {
  int g = blockIdx.x, by = blockIdx.y, t = threadIdx.x;
  int r0 = gstart[g], r1 = gstart[g + 1];
  float s = 0.f;
  for (int base = r0 + by * 128; base < r1; base += 16 * 128) {
    int lim = min(r1, base + 128);
    for (int r = base; r < lim; ++r) s += a2[(size_t)r * 256 + t];
  }
  part[((size_t)g * 16 + by) * 256 + t] = s;
}

// ---------------------------------------------------------------- fused FC head (+ pool reduce/divide)
__global__ __launch_bounds__(256) void k_head(const float* __restrict__ poolpart,
                                              const int* __restrict__ gstart,
                                              const float* __restrict__ w1, const float* __restrict__ b1,
                                              const float* __restrict__ w2, const float* __restrict__ b2,
                                              const float* __restrict__ w3, const float* __restrict__ b3,
                                              float* __restrict__ out) {
  __shared__ float p[256], z1[128], z2[64];
  int g = blockIdx.x, t = threadIdx.x;
  float s0 = 0.f;
#pragma unroll
  for (int b = 0; b < 16; ++b) s0 += poolpart[((size_t)g * 16 + b) * 256 + t];
  float cnt = (float)(gstart[g + 1] - gstart[g]);
  p[t] = s0 / fmaxf(cnt, 1.0f);
  __syncthreads();
  if (t < 128) {
    float s = b1[t];
    for (int k = 0; k < 256; ++k) s = fmaf(p[k], w1[k * 128 + t], s);
    z1[t] = fmaxf(s, 0.f);
  }
  __syncthreads();
  if (t < 64) {
    float s = b2[t];
    for (int k = 0; k < 128; ++k) s = fmaf(z1[k], w2[k * 64 + t], s);
    z2[t] = fmaxf(s, 0.f);
  }
  __syncthreads();
  if (t < 64) {
    float s = z2[t] * w3[t];
#pragma unroll
    for (int off = 32; off; off >>= 1) s += __shfl_xor(s, off);
    if (t == 0) out[g] = s + b3[0];
  }
}

// ---------------------------------------------------------------- launch
extern "C" void kernel_launch(void* const* d_in, const int* in_sizes, int n_in,
                              void* d_out, int out_size, void* d_ws, size_t ws_size,
                              hipStream_t stream) {
  const float* x    = (const float*)d_in[0];
  const int*   eidx = (const int*)d_in[1];
  const int*   batch= (const int*)d_in[2];
  const float* W1   = (const float*)d_in[3];
  const float* as1  = (const float*)d_in[4];
  const float* ad1  = (const float*)d_in[5];
  const float* b1   = (const float*)d_in[6];
  const float* g1   = (const float*)d_in[7];
  const float* be1  = (const float*)d_in[8];
  const float* W2   = (const float*)d_in[9];
  const float* as2  = (const float*)d_in[10];
  const float* ad2  = (const float*)d_in[11];
  const float* b2   = (const float*)d_in[12];
  const float* g2   = (const float*)d_in[13];
  const float* be2  = (const float*)d_in[14];
  const float* fc1w = (const float*)d_in[15];
  const float* fc1b = (const float*)d_in[16];
  const float* fc2w = (const float*)d_in[17];
  const float* fc2b = (const float*)d_in[18];
  const float* fc3w = (const float*)d_in[19];
  const float* fc3b = (const float*)d_in[20];
  float* out = (float*)d_out;
  (void)n_in; (void)out_size; (void)ws_size;

  int N = in_sizes[0] / 8;
  int E = in_sizes[1] / 2;
  const int* esrc = eidx;
  const int* edst = eidx + E;
  int nchunks = (N + 511) / 512;

  char* w = (char*)d_ws;
  auto take = [&](size_t bytes) -> char* {
    char* r = w;
    w += (bytes + 255) & ~(size_t)255;
    return r;
  };
  int*   offsets = (int*)take(4 * (size_t)(N + 1));
  int*   cursor  = (int*)take(4 * (size_t)N);
  int*   srcs    = (int*)take(4 * (size_t)(E + N));
  int*   partials= (int*)take(4 * (size_t)nchunks);
  int*   gstart  = (int*)take(4 * 65);
  float* bnstat  = (float*)take(4 * 768);
  float* bnpart  = (float*)take(4 * 128 * 512);
  float* poolpart= (float*)take(4 * 64 * 16 * 256);
  float* q1s     = (float*)take(4 * 32);
  float* q1d     = (float*)take(4 * 32);
  float* q2s     = (float*)take(4 * 512);
  float* q2d     = (float*)take(4 * 512);
  float* ssrc1   = (float*)take(16 * (size_t)N);
  float* sdst1   = (float*)take(16 * (size_t)N);
  float* ssrc2   = (float*)take(16 * (size_t)N);
  float* sdst2   = (float*)take(16 * (size_t)N);
  float* agg1    = (float*)take(4 * (size_t)N * 32);
  float* o1      = (float*)take(4 * (size_t)N * 128);   // -> a1 in place
  float* agg2    = (float*)take(4 * (size_t)N * 512);   // [4][N][128]
  float* o2      = (float*)take(4 * (size_t)N * 256);

  float* sum1 = bnstat;       float* sq1 = bnstat + 128;
  float* sum2 = bnstat + 256; float* sq2 = bnstat + 512;

  k_init<<<196, 256, 0, stream>>>(cursor, N);
  k_prep<<<1, 256, 0, stream>>>(W1, as1, ad1, W2, as2, ad2, q1s, q1d, q2s, q2d);
  k_hist<<<2048, 256, 0, stream>>>(edst, E, cursor, batch, N, gstart);
  k_scanA<<<nchunks, 512, 0, stream>>>(cursor, N, partials);
  k_scanB<<<1, 1, 0, stream>>>(partials, nchunks, offsets, N);
  k_scanC<<<nchunks, 512, 0, stream>>>(cursor, offsets, partials, N);
  k_scatter<<<2048, 256, 0, stream>>>(esrc, edst, E, N, cursor, srcs);

  k_s1<<<256, 256, 0, stream>>>(x, q1s, q1d, ssrc1, sdst1, N);
  k_agg1<<<N, 64, 0, stream>>>(x, ssrc1, sdst1, offsets, srcs, agg1);
  k_post1<<<2048, 128, 0, stream>>>(agg1, W1, b1, o1, N);
  k_bnstats<128><<<128, 128, 0, stream>>>(o1, bnpart, N);
  k_bnreduce<128><<<1, 256, 0, stream>>>(bnpart, bnstat);
  k_bns2<<<1024, 128, 0, stream>>>(o1, sum1, sq1, g1, be1, q2s, q2d, ssrc2, sdst2, N);

  k_agg2<<<N, 128, 0, stream>>>(o1, ssrc2, sdst2, offsets, srcs, agg2, N);
  k_post2<<<dim3((N + 63) / 64, 4), 256, 0, stream>>>(agg2, W2, b2, o2, N);
  k_bnstats<256><<<128, 256, 0, stream>>>(o2, bnpart, N);
  k_bnreduce<256><<<1, 512, 0, stream>>>(bnpart, bnstat + 256);
  k_bnapply<256><<<2048, 256, 0, stream>>>(o2, sum2, sq2, g2, be2, N);

  k_poolpart<<<dim3(64, 16), 256, 0, stream>>>(o2, gstart, poolpart);
  k_head<<<64, 256, 0, stream>>>(poolpart, gstart, fc1w, fc1b, fc2w, fc2b, fc3w, fc3b, out);
}

// Round 4
// 502.028 us; speedup vs baseline: 2.1464x; 1.3642x over previous
//
#include <hip/hip_runtime.h>
#include <cmath>

#define NSLOPE 0.2f
#define BN_EPS 1e-5f

static __device__ __forceinline__ float lrelu(float v) { return v > 0.f ? v : NSLOPE * v; }

// ---------------------------------------------------------------- init
__global__ void k_init(int* __restrict__ cursor, int N) {
  int i = blockIdx.x * blockDim.x + threadIdx.x;
  int stride = gridDim.x * blockDim.x;
  for (int j = i; j < N; j += stride) cursor[j] = 1;  // self-loop count
}

// in-degree histogram + graph starts via sorted-boundary writes
__global__ void k_hist(const int* __restrict__ edst, int E, int* __restrict__ cursor,
                       const int* __restrict__ batch, int N, int* __restrict__ gstart) {
  int i = blockIdx.x * blockDim.x + threadIdx.x;
  int stride = gridDim.x * blockDim.x;
  int total = E > N ? E : N;
  for (int j = i; j < total; j += stride) {
    if (j < E) atomicAdd(&cursor[edst[j]], 1);
    if (j < N) {
      int b = batch[j];
      if (j == 0) {
        for (int g = 0; g <= b; ++g) gstart[g] = 0;
      } else {
        int pb = batch[j - 1];
        if (pb != b)
          for (int g = pb + 1; g <= b; ++g) gstart[g] = j;
      }
      if (j == N - 1)
        for (int g = b + 1; g <= 64; ++g) gstart[g] = N;
    }
  }
}

// ---------------------------------------------------------------- scan (3-phase)
__global__ __launch_bounds__(512) void k_scanA(const int* __restrict__ cnt, int N,
                                               int* __restrict__ partials) {
  int t = threadIdx.x;
  int i = blockIdx.x * 512 + t;
  int v = (i < N) ? cnt[i] : 0;
#pragma unroll
  for (int off = 32; off; off >>= 1) v += __shfl_xor(v, off);
  __shared__ int red[8];
  if ((t & 63) == 0) red[t >> 6] = v;
  __syncthreads();
  if (t == 0) {
    int s = 0;
#pragma unroll
    for (int w = 0; w < 8; ++w) s += red[w];
    partials[blockIdx.x] = s;
  }
}

__global__ void k_scanB(int* __restrict__ partials, int nchunks,
                        int* __restrict__ offsets, int N) {
  if (threadIdx.x == 0 && blockIdx.x == 0) {
    int run = 0;
    for (int b = 0; b < nchunks; ++b) { int t = partials[b]; partials[b] = run; run += t; }
    offsets[N] = run;
  }
}

__global__ __launch_bounds__(512) void k_scanC(int* __restrict__ cursor, int* __restrict__ offsets,
                                               const int* __restrict__ partials, int N) {
  __shared__ int s[512];
  int t = threadIdx.x;
  int i = blockIdx.x * 512 + t;
  int c = (i < N) ? cursor[i] : 0;
  s[t] = c;
  __syncthreads();
  for (int off = 1; off < 512; off <<= 1) {
    int v = (t >= off) ? s[t - off] : 0;
    __syncthreads();
    s[t] += v;
    __syncthreads();
  }
  if (i < N) {
    int excl = s[t] - c + partials[blockIdx.x];
    offsets[i] = excl;
    cursor[i] = excl;  // scatter cursor
  }
}

__global__ void k_scatter(const int* __restrict__ esrc, const int* __restrict__ edst,
                          int E, int N, int* __restrict__ cursor, int* __restrict__ srcs) {
  int i = blockIdx.x * blockDim.x + threadIdx.x;
  int stride = gridDim.x * blockDim.x;
  int total = E + N;
  for (int j = i; j < total; j += stride) {
    int s, d;
    if (j < E) { s = esrc[j]; d = edst[j]; } else { s = j - E; d = j - E; }
    int pos = atomicAdd(&cursor[d], 1);
    srcs[pos] = s;
  }
}

// ---------------------------------------------------------------- q = W @ a  (per-head projected score vectors)
__global__ void k_prep(const float* __restrict__ W1, const float* __restrict__ as1,
                       const float* __restrict__ ad1, const float* __restrict__ W2,
                       const float* __restrict__ as2, const float* __restrict__ ad2,
                       float* __restrict__ q1s, float* __restrict__ q1d,
                       float* __restrict__ q2s, float* __restrict__ q2d) {
  int t = threadIdx.x;
  if (t < 32) {  // q1[k][h], k<8, h<4
    int k = t >> 2, h = t & 3;
    float s = 0.f, d = 0.f;
    for (int c = 0; c < 32; ++c) {
      float w = W1[k * 128 + h * 32 + c];
      s = fmaf(w, as1[h * 32 + c], s);
      d = fmaf(w, ad1[h * 32 + c], d);
    }
    q1s[t] = s; q1d[t] = d;
  }
  for (int i = t; i < 512; i += 256) {  // q2[k][h], k<128, h<4
    int k = i >> 2, h = i & 3;
    float s = 0.f, d = 0.f;
    for (int c = 0; c < 64; ++c) {
      float w = W2[k * 256 + h * 64 + c];
      s = fmaf(w, as2[h * 64 + c], s);
      d = fmaf(w, ad2[h * 64 + c], d);
    }
    q2s[i] = s; q2d[i] = d;
  }
}

// ---------------------------------------------------------------- layer-1 scores from x
__global__ __launch_bounds__(256) void k_s1(const float* __restrict__ x,
                                            const float* __restrict__ q1s,
                                            const float* __restrict__ q1d,
                                            float* __restrict__ ssrc, float* __restrict__ sdst,
                                            int N) {
  __shared__ float qs[32], qd[32];
  int t = threadIdx.x;
  if (t < 32) { qs[t] = q1s[t]; qd[t] = q1d[t]; }
  __syncthreads();
  for (int n = blockIdx.x * 256 + t; n < N; n += gridDim.x * 256) {
    float4 x0 = *(const float4*)&x[n * 8];
    float4 x1 = *(const float4*)&x[n * 8 + 4];
    float xs[8] = {x0.x, x0.y, x0.z, x0.w, x1.x, x1.y, x1.z, x1.w};
    float4 rs = make_float4(0.f, 0.f, 0.f, 0.f);
    float4 rd = make_float4(0.f, 0.f, 0.f, 0.f);
#pragma unroll
    for (int k = 0; k < 8; ++k) {
      rs.x = fmaf(xs[k], qs[k * 4 + 0], rs.x);
      rs.y = fmaf(xs[k], qs[k * 4 + 1], rs.y);
      rs.z = fmaf(xs[k], qs[k * 4 + 2], rs.z);
      rs.w = fmaf(xs[k], qs[k * 4 + 3], rs.w);
      rd.x = fmaf(xs[k], qd[k * 4 + 0], rd.x);
      rd.y = fmaf(xs[k], qd[k * 4 + 1], rd.y);
      rd.z = fmaf(xs[k], qd[k * 4 + 2], rd.z);
      rd.w = fmaf(xs[k], qd[k * 4 + 3], rd.w);
    }
    *(float4*)&ssrc[n * 4] = rs;
    *(float4*)&sdst[n * 4] = rd;
  }
}

// ---------------------------------------------------------------- layer-1 aggregation in x-space (32B/edge gather)
__global__ __launch_bounds__(64) void k_agg1(const float* __restrict__ x,
                                             const float* __restrict__ ssrc,
                                             const float* __restrict__ sdst,
                                             const int* __restrict__ offsets,
                                             const int* __restrict__ srcs,
                                             float* __restrict__ agg /*[N][4][8]*/) {
  constexpr int CHUNK = 256;
  __shared__ float4 sc[CHUNK];
  __shared__ int sidx[CHUNK];
  __shared__ float mrun[4], drun[4], scA[4];
  int n = blockIdx.x, t = threadIdx.x;
  int k = t & 7, es = t >> 3;  // feature, edge-slot
  int beg = offsets[n], deg = offsets[n + 1] - beg;
  float4 sd = *(const float4*)&sdst[n * 4];
  if (t < 4) { mrun[t] = -INFINITY; drun[t] = 0.f; }
  __syncthreads();
  float a0 = 0.f, a1v = 0.f, a2v = 0.f, a3v = 0.f;
  for (int c0 = 0; c0 < deg; c0 += CHUNK) {
    int cn = min(CHUNK, deg - c0);
    int cn8 = (cn + 7) & ~7;
    float lm0 = -INFINITY, lm1 = -INFINITY, lm2 = -INFINITY, lm3 = -INFINITY;
    for (int e = t; e < cn8; e += 64) {
      if (e < cn) {
        int s = srcs[beg + c0 + e];
        sidx[e] = s;
        float4 sv = *(const float4*)&ssrc[s * 4];
        float4 v;
        v.x = lrelu(sv.x + sd.x);
        v.y = lrelu(sv.y + sd.y);
        v.z = lrelu(sv.z + sd.z);
        v.w = lrelu(sv.w + sd.w);
        sc[e] = v;
        lm0 = fmaxf(lm0, v.x); lm1 = fmaxf(lm1, v.y);
        lm2 = fmaxf(lm2, v.z); lm3 = fmaxf(lm3, v.w);
      } else {
        sidx[e] = 0;
      }
    }
#pragma unroll
    for (int off = 32; off; off >>= 1) {
      lm0 = fmaxf(lm0, __shfl_xor(lm0, off));
      lm1 = fmaxf(lm1, __shfl_xor(lm1, off));
      lm2 = fmaxf(lm2, __shfl_xor(lm2, off));
      lm3 = fmaxf(lm3, __shfl_xor(lm3, off));
    }
    if (t == 0) {
      float o, m;
      o = mrun[0]; m = fmaxf(o, lm0); scA[0] = expf(o - m); mrun[0] = m;
      o = mrun[1]; m = fmaxf(o, lm1); scA[1] = expf(o - m); mrun[1] = m;
      o = mrun[2]; m = fmaxf(o, lm2); scA[2] = expf(o - m); mrun[2] = m;
      o = mrun[3]; m = fmaxf(o, lm3); scA[3] = expf(o - m); mrun[3] = m;
    }
    __syncthreads();
    float m0 = mrun[0], m1 = mrun[1], m2 = mrun[2], m3 = mrun[3];
    float ls0 = 0.f, ls1 = 0.f, ls2 = 0.f, ls3 = 0.f;
    for (int e = t; e < cn8; e += 64) {
      float4 v;
      if (e < cn) {
        v = sc[e];
        v.x = expf(v.x - m0); v.y = expf(v.y - m1);
        v.z = expf(v.z - m2); v.w = expf(v.w - m3);
      } else {
        v = make_float4(0.f, 0.f, 0.f, 0.f);
      }
      sc[e] = v;
      ls0 += v.x; ls1 += v.y; ls2 += v.z; ls3 += v.w;
    }
#pragma unroll
    for (int off = 32; off; off >>= 1) {
      ls0 += __shfl_xor(ls0, off); ls1 += __shfl_xor(ls1, off);
      ls2 += __shfl_xor(ls2, off); ls3 += __shfl_xor(ls3, off);
    }
    if (t == 0) {
      drun[0] = drun[0] * scA[0] + ls0;
      drun[1] = drun[1] * scA[1] + ls1;
      drun[2] = drun[2] * scA[2] + ls2;
      drun[3] = drun[3] * scA[3] + ls3;
    }
    __syncthreads();
    float sA0 = scA[0], sA1 = scA[1], sA2 = scA[2], sA3 = scA[3];
    a0 *= sA0; a1v *= sA1; a2v *= sA2; a3v *= sA3;
    for (int e = es; e < cn8; e += 8) {
      int s = sidx[e];
      float v = x[s * 8 + k];
      float4 w = sc[e];
      a0 = fmaf(w.x, v, a0); a1v = fmaf(w.y, v, a1v);
      a2v = fmaf(w.z, v, a2v); a3v = fmaf(w.w, v, a3v);
    }
    __syncthreads();
  }
#pragma unroll
  for (int off = 8; off < 64; off <<= 1) {
    a0 += __shfl_xor(a0, off); a1v += __shfl_xor(a1v, off);
    a2v += __shfl_xor(a2v, off); a3v += __shfl_xor(a3v, off);
  }
  if (es == 0) {
    agg[n * 32 + 0 + k]  = a0 / drun[0];
    agg[n * 32 + 8 + k]  = a1v / drun[1];
    agg[n * 32 + 16 + k] = a2v / drun[2];
    agg[n * 32 + 24 + k] = a3v / drun[3];
  }
}

// ---------------------------------------------------------------- out1 = agg1 @ W1 (per head) + b1, fused BN1 partial stats
__global__ __launch_bounds__(128) void k_post1(const float* __restrict__ agg,
                                               const float* __restrict__ W1,
                                               const float* __restrict__ b1,
                                               float* __restrict__ o1,
                                               float* __restrict__ part, int N) {
  int t = threadIdx.x;
  __shared__ float ag[32];
  float bb = b1[t];
  float wc[8];
#pragma unroll
  for (int k = 0; k < 8; ++k) wc[k] = W1[k * 128 + t];
  int h = t >> 5;
  float s = 0.f, s2 = 0.f;
  for (int n = blockIdx.x; n < N; n += gridDim.x) {
    if (t < 32) ag[t] = agg[n * 32 + t];
    __syncthreads();
    float v = bb;
#pragma unroll
    for (int k = 0; k < 8; ++k) v = fmaf(ag[h * 8 + k], wc[k], v);
    o1[(size_t)n * 128 + t] = v;
    s += v; s2 += v * v;
    __syncthreads();
  }
  part[(size_t)blockIdx.x * 256 + t] = s;
  part[(size_t)blockIdx.x * 256 + 128 + t] = s2;
}

// ---------------------------------------------------------------- BN2 stats (1024-block partials)
__global__ __launch_bounds__(256) void k_bnstats256(const float* __restrict__ x,
                                                    float* __restrict__ part, int N) {
  int t = threadIdx.x, b = blockIdx.x;
  float s = 0.f, s2 = 0.f;
  for (int r = b; r < N; r += gridDim.x) {
    float v = x[(size_t)r * 256 + t];
    s += v; s2 += v * v;
  }
  part[(size_t)b * 512 + t] = s;
  part[(size_t)b * 512 + 256 + t] = s2;
}

// ---------------------------------------------------------------- parallel partial reduce: stat[j] = sum_b part[b*TWO_F + j]
template <int NB, int TWO_F>
__global__ __launch_bounds__(256) void k_bnreduce2(const float* __restrict__ part,
                                                   float* __restrict__ stat) {
  int j = blockIdx.x, t = threadIdx.x;
  float s = 0.f;
  for (int b = t; b < NB; b += 256) s += part[(size_t)b * TWO_F + j];
#pragma unroll
  for (int off = 32; off; off >>= 1) s += __shfl_xor(s, off);
  __shared__ float red[4];
  if ((t & 63) == 0) red[t >> 6] = s;
  __syncthreads();
  if (t == 0) stat[j] = (red[0] + red[1]) + (red[2] + red[3]);
}

// ---------------------------------------------------------------- BN1 apply + ELU + fused layer-2 scores
__global__ __launch_bounds__(128) void k_bns2(float* __restrict__ xio,
                                              const float* __restrict__ sum,
                                              const float* __restrict__ sq,
                                              const float* __restrict__ gamma,
                                              const float* __restrict__ beta,
                                              const float* __restrict__ q2s,
                                              const float* __restrict__ q2d,
                                              float* __restrict__ ssrc2,
                                              float* __restrict__ sdst2, int N) {
  int t = threadIdx.x;
  float mean = sum[t] * (1.0f / N);
  float var = sq[t] * (1.0f / N) - mean * mean;
  float inv = rsqrtf(var + BN_EPS);
  float ga = gamma[t], be = beta[t];
  float4 qs = *(const float4*)&q2s[t * 4];
  float4 qd = *(const float4*)&q2d[t * 4];
  __shared__ float redv[2][8];
  int wid = t >> 6, lane = t & 63;
  for (int r = blockIdx.x; r < N; r += gridDim.x) {
    float v = xio[(size_t)r * 128 + t];
    float y = ga * ((v - mean) * inv) + be;
    y = y > 0.f ? y : expm1f(y);
    xio[(size_t)r * 128 + t] = y;
    float p0 = y * qs.x, p1 = y * qs.y, p2 = y * qs.z, p3 = y * qs.w;
    float d0 = y * qd.x, d1 = y * qd.y, d2 = y * qd.z, d3 = y * qd.w;
#pragma unroll
    for (int off = 32; off; off >>= 1) {
      p0 += __shfl_xor(p0, off); p1 += __shfl_xor(p1, off);
      p2 += __shfl_xor(p2, off); p3 += __shfl_xor(p3, off);
      d0 += __shfl_xor(d0, off); d1 += __shfl_xor(d1, off);
      d2 += __shfl_xor(d2, off); d3 += __shfl_xor(d3, off);
    }
    if (lane == 0) {
      redv[wid][0] = p0; redv[wid][1] = p1; redv[wid][2] = p2; redv[wid][3] = p3;
      redv[wid][4] = d0; redv[wid][5] = d1; redv[wid][6] = d2; redv[wid][7] = d3;
    }
    __syncthreads();
    if (t < 8) {
      float s = redv[0][t] + redv[1][t];
      if (t < 4) ssrc2[r * 4 + t] = s;
      else sdst2[r * 4 + (t - 4)] = s;
    }
    __syncthreads();
  }
}

// ---------------------------------------------------------------- layer-2 aggregation in a1-space (512B/edge gather)
__global__ __launch_bounds__(128) void k_agg2(const float* __restrict__ a1,
                                              const float* __restrict__ ssrc,
                                              const float* __restrict__ sdst,
                                              const int* __restrict__ offsets,
                                              const int* __restrict__ srcs,
                                              float* __restrict__ agg /*[4][N][128]*/, int N) {
  constexpr int CHUNK = 512;
  __shared__ float4 sc[CHUNK];
  __shared__ int sidx[CHUNK];
  __shared__ float red[2][4];
  __shared__ float mrun[4], drun[4], scA[4];
  int n = blockIdx.x, t = threadIdx.x;
  int wid = t >> 6, lane = t & 63;
  int beg = offsets[n], deg = offsets[n + 1] - beg;
  float4 sd = *(const float4*)&sdst[n * 4];
  if (t < 4) { mrun[t] = -INFINITY; drun[t] = 0.f; }
  __syncthreads();
  float aA0 = 0.f, aA1 = 0.f, aA2 = 0.f, aA3 = 0.f;
  float aB0 = 0.f, aB1 = 0.f, aB2 = 0.f, aB3 = 0.f;
  for (int c0 = 0; c0 < deg; c0 += CHUNK) {
    int cn = min(CHUNK, deg - c0);
    int cn4 = (cn + 3) & ~3;
    float lm0 = -INFINITY, lm1 = -INFINITY, lm2 = -INFINITY, lm3 = -INFINITY;
    for (int e = t; e < cn4; e += 128) {
      if (e < cn) {
        int s = srcs[beg + c0 + e];
        sidx[e] = s;
        float4 sv = *(const float4*)&ssrc[s * 4];
        float4 v;
        v.x = lrelu(sv.x + sd.x);
        v.y = lrelu(sv.y + sd.y);
        v.z = lrelu(sv.z + sd.z);
        v.w = lrelu(sv.w + sd.w);
        sc[e] = v;
        lm0 = fmaxf(lm0, v.x); lm1 = fmaxf(lm1, v.y);
        lm2 = fmaxf(lm2, v.z); lm3 = fmaxf(lm3, v.w);
      } else {
        sidx[e] = 0;
      }
    }
#pragma unroll
    for (int off = 32; off; off >>= 1) {
      lm0 = fmaxf(lm0, __shfl_xor(lm0, off));
      lm1 = fmaxf(lm1, __shfl_xor(lm1, off));
      lm2 = fmaxf(lm2, __shfl_xor(lm2, off));
      lm3 = fmaxf(lm3, __shfl_xor(lm3, off));
    }
    if (lane == 0) { red[wid][0] = lm0; red[wid][1] = lm1; red[wid][2] = lm2; red[wid][3] = lm3; }
    __syncthreads();
    if (t < 4) {
      float mm = fmaxf(red[0][t], red[1][t]);
      float old = mrun[t];
      float mn = fmaxf(old, mm);
      scA[t] = expf(old - mn);
      mrun[t] = mn;
    }
    __syncthreads();
    float m0 = mrun[0], m1 = mrun[1], m2 = mrun[2], m3 = mrun[3];
    float ls0 = 0.f, ls1 = 0.f, ls2 = 0.f, ls3 = 0.f;
    for (int e = t; e < cn4; e += 128) {
      float4 v;
      if (e < cn) {
        v = sc[e];
        v.x = expf(v.x - m0); v.y = expf(v.y - m1);
        v.z = expf(v.z - m2); v.w = expf(v.w - m3);
      } else {
        v = make_float4(0.f, 0.f, 0.f, 0.f);
      }
      sc[e] = v;
      ls0 += v.x; ls1 += v.y; ls2 += v.z; ls3 += v.w;
    }
#pragma unroll
    for (int off = 32; off; off >>= 1) {
      ls0 += __shfl_xor(ls0, off); ls1 += __shfl_xor(ls1, off);
      ls2 += __shfl_xor(ls2, off); ls3 += __shfl_xor(ls3, off);
    }
    if (lane == 0) { red[wid][0] = ls0; red[wid][1] = ls1; red[wid][2] = ls2; red[wid][3] = ls3; }
    __syncthreads();
    if (t < 4) drun[t] = drun[t] * scA[t] + (red[0][t] + red[1][t]);
    float sA0 = scA[0], sA1 = scA[1], sA2 = scA[2], sA3 = scA[3];
    aA0 *= sA0; aB0 *= sA0; aA1 *= sA1; aB1 *= sA1;
    aA2 *= sA2; aB2 *= sA2; aA3 *= sA3; aB3 *= sA3;
    for (int e = 0; e < cn4; e += 4) {
      int i0 = sidx[e], i1 = sidx[e + 1], i2 = sidx[e + 2], i3 = sidx[e + 3];
      float v0 = a1[(size_t)i0 * 128 + t];
      float v1 = a1[(size_t)i1 * 128 + t];
      float v2 = a1[(size_t)i2 * 128 + t];
      float v3 = a1[(size_t)i3 * 128 + t];
      float4 w0 = sc[e], w1 = sc[e + 1], w2 = sc[e + 2], w3 = sc[e + 3];
      aA0 = fmaf(w0.x, v0, aA0); aA1 = fmaf(w0.y, v0, aA1);
      aA2 = fmaf(w0.z, v0, aA2); aA3 = fmaf(w0.w, v0, aA3);
      aB0 = fmaf(w1.x, v1, aB0); aB1 = fmaf(w1.y, v1, aB1);
      aB2 = fmaf(w1.z, v1, aB2); aB3 = fmaf(w1.w, v1, aB3);
      aA0 = fmaf(w2.x, v2, aA0); aA1 = fmaf(w2.y, v2, aA1);
      aA2 = fmaf(w2.z, v2, aA2); aA3 = fmaf(w2.w, v2, aA3);
      aB0 = fmaf(w3.x, v3, aB0); aB1 = fmaf(w3.y, v3, aB1);
      aB2 = fmaf(w3.z, v3, aB2); aB3 = fmaf(w3.w, v3, aB3);
    }
    __syncthreads();
  }
  size_t nn = (size_t)n * 128 + t;
  size_t pl = (size_t)N * 128;
  agg[nn] = (aA0 + aB0) / drun[0];
  agg[pl + nn] = (aA1 + aB1) / drun[1];
  agg[2 * pl + nn] = (aA2 + aB2) / drun[2];
  agg[3 * pl + nn] = (aA3 + aB3) / drun[3];
}

// ---------------------------------------------------------------- out2 = per-head [N,128]@[128,64] + b2
__global__ __launch_bounds__(256) void k_post2(const float* __restrict__ agg,
                                               const float* __restrict__ W2,
                                               const float* __restrict__ b2,
                                               float* __restrict__ out, int N) {
  __shared__ float As[128][64];
  __shared__ float Bs[128][64];
  int h = blockIdx.y;
  int m0 = blockIdx.x * 64;
  int tid = threadIdx.x;
  const float* Ap = agg + (size_t)h * N * 128;
  {
    int ml = tid & 63, kg = tid >> 6;
    const float* arow = Ap + (size_t)(m0 + ml) * 128;
    bool rok = (m0 + ml) < N;
#pragma unroll
    for (int it = 0; it < 8; ++it) {
      int k4 = kg + 4 * it;
      float4 v = rok ? *(const float4*)(arow + k4 * 4) : make_float4(0.f, 0.f, 0.f, 0.f);
      As[k4 * 4 + 0][ml] = v.x;
      As[k4 * 4 + 1][ml] = v.y;
      As[k4 * 4 + 2][ml] = v.z;
      As[k4 * 4 + 3][ml] = v.w;
    }
  }
  {
    int c4 = tid & 15, k0 = tid >> 4;  // 16 row-groups
    for (int k = k0; k < 128; k += 16) {
      float4 v = *(const float4*)&W2[(size_t)k * 256 + h * 64 + c4 * 4];
      *(float4*)&Bs[k][c4 * 4] = v;
    }
  }
  __syncthreads();
  int tx = tid & 15, ty = tid >> 4;
  float acc[4][4];
#pragma unroll
  for (int r = 0; r < 4; ++r)
#pragma unroll
    for (int c = 0; c < 4; ++c) acc[r][c] = 0.f;
#pragma unroll 2
  for (int k = 0; k < 128; ++k) {
    float4 a4 = *(const float4*)&As[k][ty * 4];
    float4 b4 = *(const float4*)&Bs[k][tx * 4];
    float av[4] = {a4.x, a4.y, a4.z, a4.w};
    float bv[4] = {b4.x, b4.y, b4.z, b4.w};
#pragma unroll
    for (int r = 0; r < 4; ++r)
#pragma unroll
      for (int c = 0; c < 4; ++c) acc[r][c] = fmaf(av[r], bv[c], acc[r][c]);
  }
  float4 bb = *(const float4*)&b2[h * 64 + tx * 4];
#pragma unroll
  for (int r = 0; r < 4; ++r) {
    int row = m0 + ty * 4 + r;
    if (row < N) {
      float4 c4;
      c4.x = acc[r][0] + bb.x; c4.y = acc[r][1] + bb.y;
      c4.z = acc[r][2] + bb.z; c4.w = acc[r][3] + bb.w;
      *(float4*)&out[(size_t)row * 256 + h * 64 + tx * 4] = c4;
    }
  }
}

// ---------------------------------------------------------------- BN apply + ELU (elementwise)
template <int F>
__global__ void k_bnapply(float* __restrict__ x, const float* __restrict__ sum,
                          const float* __restrict__ sq, const float* __restrict__ gamma,
                          const float* __restrict__ beta, int N) {
  size_t total = (size_t)N * F;
  size_t stride = (size_t)gridDim.x * blockDim.x;
  for (size_t idx = (size_t)blockIdx.x * blockDim.x + threadIdx.x; idx < total; idx += stride) {
    int c = (int)(idx & (F - 1));
    float mean = sum[c] * (1.0f / N);
    float var = sq[c] * (1.0f / N) - mean * mean;
    float inv = rsqrtf(var + BN_EPS);
    float y = gamma[c] * ((x[idx] - mean) * inv) + beta[c];
    x[idx] = y > 0.f ? y : expm1f(y);
  }
}

// ---------------------------------------------------------------- mean pool partials per (graph, chunk)
__global__ __launch_bounds__(256) void k_poolpart(const float* __restrict__ a2,
                                                  const int* __restrict__ gstart,
                                                  float* __restrict__ part) {
  int g = blockIdx.x, by = blockIdx.y, t = threadIdx.x;
  int r0 = gstart[g], r1 = gstart[g + 1];
  float s = 0.f;
  for (int base = r0 + by * 128; base < r1; base += 16 * 128) {
    int lim = min(r1, base + 128);
    for (int r = base; r < lim; ++r) s += a2[(size_t)r * 256 + t];
  }
  part[((size_t)g * 16 + by) * 256 + t] = s;
}

// ---------------------------------------------------------------- fused FC head (+ pool reduce/divide)
__global__ __launch_bounds__(256) void k_head(const float* __restrict__ poolpart,
                                              const int* __restrict__ gstart,
                                              const float* __restrict__ w1, const float* __restrict__ b1,
                                              const float* __restrict__ w2, const float* __restrict__ b2,
                                              const float* __restrict__ w3, const float* __restrict__ b3,
                                              float* __restrict__ out) {
  __shared__ float p[256], z1[128], z2[64];
  int g = blockIdx.x, t = threadIdx.x;
  float s0 = 0.f;
#pragma unroll
  for (int b = 0; b < 16; ++b) s0 += poolpart[((size_t)g * 16 + b) * 256 + t];
  float cnt = (float)(gstart[g + 1] - gstart[g]);
  p[t] = s0 / fmaxf(cnt, 1.0f);
  __syncthreads();
  if (t < 128) {
    float s = b1[t];
    for (int k = 0; k < 256; ++k) s = fmaf(p[k], w1[k * 128 + t], s);
    z1[t] = fmaxf(s, 0.f);
  }
  __syncthreads();
  if (t < 64) {
    float s = b2[t];
    for (int k = 0; k < 128; ++k) s = fmaf(z1[k], w2[k * 64 + t], s);
    z2[t] = fmaxf(s, 0.f);
  }
  __syncthreads();
  if (t < 64) {
    float s = z2[t] * w3[t];
#pragma unroll
    for (int off = 32; off; off >>= 1) s += __shfl_xor(s, off);
    if (t == 0) out[g] = s + b3[0];
  }
}

// ---------------------------------------------------------------- launch
extern "C" void kernel_launch(void* const* d_in, const int* in_sizes, int n_in,
                              void* d_out, int out_size, void* d_ws, size_t ws_size,
                              hipStream_t stream) {
  const float* x    = (const float*)d_in[0];
  const int*   eidx = (const int*)d_in[1];
  const int*   batch= (const int*)d_in[2];
  const float* W1   = (const float*)d_in[3];
  const float* as1  = (const float*)d_in[4];
  const float* ad1  = (const float*)d_in[5];
  const float* b1   = (const float*)d_in[6];
  const float* g1   = (const float*)d_in[7];
  const float* be1  = (const float*)d_in[8];
  const float* W2   = (const float*)d_in[9];
  const float* as2  = (const float*)d_in[10];
  const float* ad2  = (const float*)d_in[11];
  const float* b2   = (const float*)d_in[12];
  const float* g2   = (const float*)d_in[13];
  const float* be2  = (const float*)d_in[14];
  const float* fc1w = (const float*)d_in[15];
  const float* fc1b = (const float*)d_in[16];
  const float* fc2w = (const float*)d_in[17];
  const float* fc2b = (const float*)d_in[18];
  const float* fc3w = (const float*)d_in[19];
  const float* fc3b = (const float*)d_in[20];
  float* out = (float*)d_out;
  (void)n_in; (void)out_size; (void)ws_size;

  int N = in_sizes[0] / 8;
  int E = in_sizes[1] / 2;
  const int* esrc = eidx;
  const int* edst = eidx + E;
  int nchunks = (N + 511) / 512;

  char* w = (char*)d_ws;
  auto take = [&](size_t bytes) -> char* {
    char* r = w;
    w += (bytes + 255) & ~(size_t)255;
    return r;
  };
  int*   offsets = (int*)take(4 * (size_t)(N + 1));
  int*   cursor  = (int*)take(4 * (size_t)N);
  int*   srcs    = (int*)take(4 * (size_t)(E + N));
  int*   partials= (int*)take(4 * (size_t)nchunks);
  int*   gstart  = (int*)take(4 * 65);
  float* bnstat  = (float*)take(4 * 1024);
  float* bnpart  = (float*)take(4 * 524288);           // 2048*256 == 1024*512
  float* poolpart= (float*)take(4 * 64 * 16 * 256);
  float* q1s     = (float*)take(4 * 32);
  float* q1d     = (float*)take(4 * 32);
  float* q2s     = (float*)take(4 * 512);
  float* q2d     = (float*)take(4 * 512);
  float* ssrc1   = (float*)take(16 * (size_t)N);
  float* sdst1   = (float*)take(16 * (size_t)N);
  float* ssrc2   = (float*)take(16 * (size_t)N);
  float* sdst2   = (float*)take(16 * (size_t)N);
  float* agg1    = (float*)take(4 * (size_t)N * 32);
  float* o1      = (float*)take(4 * (size_t)N * 128);   // -> a1 in place
  float* agg2    = (float*)take(4 * (size_t)N * 512);   // [4][N][128]
  float* o2      = (float*)take(4 * (size_t)N * 256);

  float* sum1 = bnstat;       float* sq1 = bnstat + 128;
  float* sum2 = bnstat + 256; float* sq2 = bnstat + 512;

  k_init<<<196, 256, 0, stream>>>(cursor, N);
  k_prep<<<1, 256, 0, stream>>>(W1, as1, ad1, W2, as2, ad2, q1s, q1d, q2s, q2d);
  k_hist<<<2048, 256, 0, stream>>>(edst, E, cursor, batch, N, gstart);
  k_scanA<<<nchunks, 512, 0, stream>>>(cursor, N, partials);
  k_scanB<<<1, 1, 0, stream>>>(partials, nchunks, offsets, N);
  k_scanC<<<nchunks, 512, 0, stream>>>(cursor, offsets, partials, N);
  k_scatter<<<2048, 256, 0, stream>>>(esrc, edst, E, N, cursor, srcs);

  k_s1<<<256, 256, 0, stream>>>(x, q1s, q1d, ssrc1, sdst1, N);
  k_agg1<<<N, 64, 0, stream>>>(x, ssrc1, sdst1, offsets, srcs, agg1);
  k_post1<<<2048, 128, 0, stream>>>(agg1, W1, b1, o1, bnpart, N);
  k_bnreduce2<2048, 256><<<256, 256, 0, stream>>>(bnpart, bnstat);
  k_bns2<<<1024, 128, 0, stream>>>(o1, sum1, sq1, g1, be1, q2s, q2d, ssrc2, sdst2, N);

  k_agg2<<<N, 128, 0, stream>>>(o1, ssrc2, sdst2, offsets, srcs, agg2, N);
  k_post2<<<dim3((N + 63) / 64, 4), 256, 0, stream>>>(agg2, W2, b2, o2, N);
  k_bnstats256<<<1024, 256, 0, stream>>>(o2, bnpart, N);
  k_bnreduce2<1024, 512><<<512, 256, 0, stream>>>(bnpart, bnstat + 256);
  k_bnapply<256><<<2048, 256, 0, stream>>>(o2, sum2, sq2, g2, be2, N);

  k_poolpart<<<dim3(64, 16), 256, 0, stream>>>(o2, gstart, poolpart);
  k_head<<<64, 256, 0, stream>>>(poolpart, gstart, fc1w, fc1b, fc2w, fc2b, fc3w, fc3b, out);
}